// Round 15
// baseline (8540.186 us; speedup 1.0000x reference)
//
#include <hip/hip_runtime.h>

typedef unsigned short u16;
typedef unsigned int   u32;
typedef __attribute__((ext_vector_type(8))) short short8;
typedef __attribute__((ext_vector_type(4))) float f32x4;

#define NN  10000
#define EGN 200000
#define TTN 300000
#define LLN 3

__device__ __forceinline__ float b2f(u16 u){ union{u32 i; float f;} x; x.i=(u32)u<<16; return x.f; }
__device__ __forceinline__ u16 f2b(float f){ union{float f; u32 u;} x; x.f=f; u32 r=(x.u + 0x7fffu + ((x.u>>16)&1u))>>16; return (u16)r; }
__device__ __forceinline__ float sigf(float x){ return 1.f/(1.f+__expf(-x)); }
__device__ __forceinline__ float tanhf_(float x){ float e=__expf(2.f*x); return 1.f - 2.f/(e+1.f); }
__device__ __forceinline__ float sspf(float x){ return fmaxf(x,0.f) + log1pf(__expf(-fabsf(x))) - 0.6931471805599453f; }

__device__ __forceinline__ void split_store(float v, u16* ph, u16* pl, size_t o){
  u16 h = f2b(v); ph[o] = h; pl[o] = f2b(v - b2f(h));
}
// direct fragment loads: A rows are 128 u16 (256B); chunk = 16B unit index (0..15)
__device__ __forceinline__ short8 ldA(const u16* p, int srow, int chunk){
  return *(const short8*)(p + (size_t)srow*128 + chunk*8);
}
// B: W^T row-major, K2u u16 per row
__device__ __forceinline__ short8 ldBd(const u16* W, int row, int K2u, int chunk){
  return *(const short8*)(W + (size_t)row*K2u + chunk*8);
}
__device__ __forceinline__ void prodfrag(const u16* nh, const u16* nl, int ri, int rj, int chunk,
                                         short8& vh, short8& vl){
  short8 hi = *(const short8*)(nh + (size_t)ri*128 + chunk*8);
  short8 li = *(const short8*)(nl + (size_t)ri*128 + chunk*8);
  short8 hj = *(const short8*)(nh + (size_t)rj*128 + chunk*8);
  short8 lj = *(const short8*)(nl + (size_t)rj*128 + chunk*8);
#pragma unroll
  for (int k=0;k<8;k++){
    float a = b2f((u16)hi[k]) + b2f((u16)li[k]);
    float b = b2f((u16)hj[k]) + b2f((u16)lj[k]);
    float v = a*b;
    u16 h = f2b(v);
    vh[k] = (short)h;
    vl[k] = (short)f2b(v - b2f(h));
  }
}

struct Segs {
  const u16* sh[5];
  const u16* sl[5];
  const int* idx[5];    // nullptr = identity rows
};

// ---------- K1: stats-only GEMM (A hi plane). 64 rows x ALL 256 cols, barrier-free ----------
template<int NSRC, bool PROD>
__global__ __launch_bounds__(256) void gemm_stats(
  int M, Segs segs,
  const u16* __restrict__ nh, const u16* __restrict__ nl,
  const int* __restrict__ pii, const int* __restrict__ pjj,
  const u16* __restrict__ Wh, const float* __restrict__ bias,
  float* __restrict__ st)
{
  __shared__ float ls[256], lq[256];
  const int tid = threadIdx.x, lane = tid&63, wv = tid>>6;
  const int lane15 = lane&15, kg = lane>>4;
  const int rb = blockIdx.x*64;
  const int K2u = NSRC*128;
  ls[tid]=0.f; lq[tid]=0.f;

  int srI[4], srJ[4];
  int srow[NSRC][4];
#pragma unroll
  for (int m=0;m<4;m++){
    int grow = rb + m*16 + lane15; if (grow >= M) grow = M-1;
    if (PROD){ srI[m]=pii[grow]; srJ[m]=pjj[grow]; }
    else {
#pragma unroll
      for (int s=0;s<NSRC;s++) srow[s][m] = segs.idx[s] ? segs.idx[s][grow] : grow;
    }
  }

  f32x4 acc[4][4];
#pragma unroll
  for (int m=0;m<4;m++)
#pragma unroll
    for (int n=0;n<4;n++) acc[m][n] = (f32x4){0.f,0.f,0.f,0.f};

#pragma unroll
  for (int s=0;s<NSRC;s++){
#pragma unroll
    for (int stp=0;stp<4;stp++){
      const int ch = stp*4 + kg;
      const int bch = s*16 + ch;
      short8 a[4];
      if (PROD){
#pragma unroll
        for (int m=0;m<4;m++){ short8 vl_; prodfrag(nh,nl,srI[m],srJ[m],ch,a[m],vl_); }
      } else {
#pragma unroll
        for (int m=0;m<4;m++) a[m] = ldA(segs.sh[s], srow[s][m], ch);
      }
      short8 b[4];
#pragma unroll
      for (int n=0;n<4;n++) b[n] = ldBd(Wh, wv*64 + n*16 + lane15, K2u, bch);
#pragma unroll
      for (int n=0;n<4;n++)
#pragma unroll
        for (int m=0;m<4;m++)
          acc[m][n] = __builtin_amdgcn_mfma_f32_16x16x32_bf16(a[m], b[n], acc[m][n], 0,0,0);
    }
  }

  __syncthreads();   // ls/lq init visible before LDS atomics
#pragma unroll
  for (int n=0;n<4;n++){
    int col = wv*64 + n*16 + lane15;
    float bb = bias[col];
    float s=0.f, q=0.f;
#pragma unroll
    for (int m=0;m<4;m++){
#pragma unroll
      for (int r=0;r<4;r++){
        int grow = rb + m*16 + (lane>>4)*4 + r;
        if (grow < M){ float v = acc[m][n][r] + bb; s += v; q += v*v; }
      }
    }
    s += __shfl_xor(s,16); s += __shfl_xor(s,32);
    q += __shfl_xor(q,16); q += __shfl_xor(q,32);
    if (lane < 16){ atomicAdd(&ls[wv*64 + n*16 + lane], s); atomicAdd(&lq[wv*64 + n*16 + lane], q); }
  }
  __syncthreads();
  atomicAdd(&st[tid], ls[tid]); atomicAdd(&st[256+tid], lq[tid]);
}

// ---------- K2: paired GEMM. 64 rows x 64 pairs, barrier-free K-loop ----------
// EPI 0: scatter sig*tanh; EPI 1: edge update in place; EPI 2: stats of u
template<int NSRC, int NP, bool PROD, int EPI>
__global__ __launch_bounds__(256) void gemm_pair(
  int M, Segs segs,
  const u16* __restrict__ nh, const u16* __restrict__ nl,
  const int* __restrict__ pii, const int* __restrict__ pjj,
  const u16* __restrict__ Wh, const u16* __restrict__ Wl,
  const float* __restrict__ bias,
  const float* __restrict__ st, const float* __restrict__ g, const float* __restrict__ b, float inv,
  const int* __restrict__ sidx, float* __restrict__ aggout,
  const float* __restrict__ st22, const float* __restrict__ g22, const float* __restrict__ b22,
  const float* __restrict__ st32, const float* __restrict__ g32, const float* __restrict__ b32, float inv2,
  const float* __restrict__ agg3, u16* __restrict__ eh, u16* __restrict__ el,
  float* __restrict__ st22out)
{
  __shared__ float ls[64], lq[64];
  __shared__ float sAf[64], sCf[64], sAr[64], sCr[64];
  __shared__ float sA22[64], sC22[64], sA32[64], sC32[64];
  const int tid = threadIdx.x, lane = tid&63, wv = tid>>6;
  const int lane15 = lane&15, kg = lane>>4;
  const int rb = blockIdx.x*64, P0 = blockIdx.y*64;
  const int K2u = NSRC*128;

  if (tid < 64){
    int p = P0 + tid;
    float m1 = st[p]*inv,     v1 = st[256+p]*inv - m1*m1;
    float a1 = g[p]*rsqrtf(v1+1e-5f);
    sAf[tid]=a1; sCf[tid]=b[p]-a1*m1;
    float m2 = st[128+p]*inv, v2 = st[384+p]*inv - m2*m2;
    float a2 = g[128+p]*rsqrtf(v2+1e-5f);
    sAr[tid]=a2; sCr[tid]=b[128+p]-a2*m2;
    if (EPI==1){
      float m3 = st22[p]*inv2, v3 = st22[128+p]*inv2 - m3*m3;
      float a3 = g22[p]*rsqrtf(v3+1e-5f);
      sA22[tid]=a3; sC22[tid]=b22[p]-a3*m3;
      float m4 = st32[p]*inv2, v4 = st32[128+p]*inv2 - m4*m4;
      float a4 = g32[p]*rsqrtf(v4+1e-5f);
      sA32[tid]=a4; sC32[tid]=b32[p]-a4*m4;
    }
    if (EPI==2){ ls[tid]=0.f; lq[tid]=0.f; }
  }

  int srI[4], srJ[4];
  int srow[NSRC][4];
#pragma unroll
  for (int m=0;m<4;m++){
    int grow = rb + m*16 + lane15; if (grow >= M) grow = M-1;
    if (PROD){ srI[m]=pii[grow]; srJ[m]=pjj[grow]; }
    else {
#pragma unroll
      for (int s=0;s<NSRC;s++) srow[s][m] = segs.idx[s] ? segs.idx[s][grow] : grow;
    }
  }
  const int bRowF = P0 + wv*16 + lane15;
  const int bRowR = 128 + bRowF;

  f32x4 accf[4], accr[4];
#pragma unroll
  for (int m=0;m<4;m++){ accf[m]=(f32x4){0.f,0.f,0.f,0.f}; accr[m]=(f32x4){0.f,0.f,0.f,0.f}; }

#pragma unroll
  for (int s=0;s<NSRC;s++){
#pragma unroll
    for (int stp=0;stp<4;stp++){
      const int ch = stp*4 + kg;
      const int bch = s*16 + ch;
      short8 ah[4], al[4];
      if (PROD){
#pragma unroll
        for (int m=0;m<4;m++) prodfrag(nh,nl,srI[m],srJ[m],ch,ah[m],al[m]);
      } else {
#pragma unroll
        for (int m=0;m<4;m++){
          ah[m] = ldA(segs.sh[s], srow[s][m], ch);
          if (NP==2) al[m] = ldA(segs.sl[s], srow[s][m], ch);
        }
      }
      short8 bfh = ldBd(Wh, bRowF, K2u, bch);
      short8 brh = ldBd(Wh, bRowR, K2u, bch);
      short8 bfl, brl;
      if (NP==2){ bfl = ldBd(Wl, bRowF, K2u, bch); brl = ldBd(Wl, bRowR, K2u, bch); }
#pragma unroll
      for (int m=0;m<4;m++){
        accf[m] = __builtin_amdgcn_mfma_f32_16x16x32_bf16(ah[m], bfh, accf[m], 0,0,0);
        accr[m] = __builtin_amdgcn_mfma_f32_16x16x32_bf16(ah[m], brh, accr[m], 0,0,0);
        if (NP==2){
          accf[m] = __builtin_amdgcn_mfma_f32_16x16x32_bf16(ah[m], bfl, accf[m], 0,0,0);
          accf[m] = __builtin_amdgcn_mfma_f32_16x16x32_bf16(al[m], bfh, accf[m], 0,0,0);
          accr[m] = __builtin_amdgcn_mfma_f32_16x16x32_bf16(ah[m], brl, accr[m], 0,0,0);
          accr[m] = __builtin_amdgcn_mfma_f32_16x16x32_bf16(al[m], brh, accr[m], 0,0,0);
        }
      }
    }
  }

  __syncthreads();   // BN params / ls init visible
  const int pp = wv*16 + lane15;
  const int p  = P0 + pp;
  const float bf_ = bias[p], br_ = bias[128+p];
  const float Af = sAf[pp], Cf = sCf[pp], Ar = sAr[pp], Cr = sCr[pp];
  float su=0.f, sq=0.f;
#pragma unroll
  for (int m=0;m<4;m++){
#pragma unroll
    for (int r=0;r<4;r++){
      int grow = rb + m*16 + (lane>>4)*4 + r;
      if (grow >= M) continue;
      float yf = accf[m][r] + bf_;
      float yr = accr[m][r] + br_;
      float u = sigf(Af*yf + Cf) * tanhf_(Ar*yr + Cr);
      if (EPI==0){
        atomicAdd(&aggout[(size_t)sidx[grow]*128 + p], u);
      } else if (EPI==1){
        size_t o = (size_t)grow*128 + p;
        float eo = b2f(eh[o]) + b2f(el[o]);
        float v = tanhf_(eo + sA22[pp]*u + sC22[pp] + sA32[pp]*agg3[o] + sC32[pp]);
        split_store(v, eh, el, o);
      } else {
        su += u; sq += u*u;
      }
    }
  }
  if (EPI==2){
    su += __shfl_xor(su,16); su += __shfl_xor(su,32);
    sq += __shfl_xor(sq,16); sq += __shfl_xor(sq,32);
    if (lane < 16){ atomicAdd(&ls[wv*16+lane], su); atomicAdd(&lq[wv*16+lane], sq); }
    __syncthreads();
    if (tid < 64){ atomicAdd(&st22out[P0+tid], ls[tid]); atomicAdd(&st22out[128+P0+tid], lq[tid]); }
  }
}

// ---------- K3: force GEMM (split, 64 rows x 128 cols), barrier-free ----------
__global__ __launch_bounds__(256) void gemm_force(
  int M, const u16* __restrict__ Ahp, const u16* __restrict__ Alp,
  const u16* __restrict__ Wh, const u16* __restrict__ Wl,
  const float* __restrict__ bias, u16* __restrict__ oh, u16* __restrict__ ol)
{
  const int tid = threadIdx.x, lane = tid&63, wv = tid>>6;
  const int lane15 = lane&15, kg = lane>>4;
  const int rb = blockIdx.x*64;

  int srow[4];
#pragma unroll
  for (int m=0;m<4;m++){
    int grow = rb + m*16 + lane15; if (grow >= M) grow = M-1;
    srow[m] = grow;
  }

  f32x4 acc[4][2];
#pragma unroll
  for (int m=0;m<4;m++)
#pragma unroll
    for (int n=0;n<2;n++) acc[m][n] = (f32x4){0.f,0.f,0.f,0.f};

#pragma unroll
  for (int stp=0;stp<4;stp++){
    const int ch = stp*4 + kg;
    short8 ah[4], al[4];
#pragma unroll
    for (int m=0;m<4;m++){
      ah[m] = ldA(Ahp, srow[m], ch);
      al[m] = ldA(Alp, srow[m], ch);
    }
#pragma unroll
    for (int n=0;n<2;n++){
      short8 bh = ldBd(Wh, wv*32 + n*16 + lane15, 128, ch);
      short8 bl = ldBd(Wl, wv*32 + n*16 + lane15, 128, ch);
#pragma unroll
      for (int m=0;m<4;m++){
        acc[m][n] = __builtin_amdgcn_mfma_f32_16x16x32_bf16(ah[m], bh, acc[m][n], 0,0,0);
        acc[m][n] = __builtin_amdgcn_mfma_f32_16x16x32_bf16(ah[m], bl, acc[m][n], 0,0,0);
        acc[m][n] = __builtin_amdgcn_mfma_f32_16x16x32_bf16(al[m], bh, acc[m][n], 0,0,0);
      }
    }
  }
#pragma unroll
  for (int n=0;n<2;n++){
    int col = wv*32 + n*16 + lane15;
    float bb = bias[col];
#pragma unroll
    for (int m=0;m<4;m++){
#pragma unroll
      for (int r=0;r<4;r++){
        int grow = rb + m*16 + (lane>>4)*4 + r;
        if (grow < M){
          float v = sspf(acc[m][n][r] + bb);
          split_store(v, oh, ol, (size_t)grow*128 + col);
        }
      }
    }
  }
}

// ---------- small kernels ----------
__global__ void transpose_cvt(const float* __restrict__ src, u16* __restrict__ dh, u16* __restrict__ dl, int K, int N){
  __shared__ float t[32][33];
  const float* s = src + (size_t)blockIdx.z * K * N;
  u16* dsth = dh + (size_t)blockIdx.z * K * N;
  u16* dstl = dl + (size_t)blockIdx.z * K * N;
  int n0 = blockIdx.x*32, k0 = blockIdx.y*32;
  for (int dy=threadIdx.y; dy<32; dy+=8){
    int k = k0+dy, n = n0+threadIdx.x;
    if (k<K && n<N) t[dy][threadIdx.x] = s[(size_t)k*N + n];
  }
  __syncthreads();
  for (int dy=threadIdx.y; dy<32; dy+=8){
    int n = n0+dy, k = k0+threadIdx.x;
    if (n<N && k<K) split_store(t[threadIdx.x][dy], dsth, dstl, (size_t)n*K + k);
  }
}

__global__ __launch_bounds__(128) void embed_k(const int* __restrict__ z,
  const float* __restrict__ We1, const float* __restrict__ be1,
  const float* __restrict__ We2, const float* __restrict__ be2,
  const float* __restrict__ We3, const float* __restrict__ be3,
  u16* __restrict__ nh, u16* __restrict__ nl){
  __shared__ float h0[128], h1[128];
  int nid = blockIdx.x, t = threadIdx.x;
  int zz = z[nid];
  h0[t] = sspf(We1[zz*128 + t] + be1[t]);
  __syncthreads();
  float a = be2[t];
  for (int k=0;k<128;k++) a += h0[k]*We2[k*128+t];
  h1[t] = sspf(a);
  __syncthreads();
  float b = be3[t];
  for (int k=0;k<128;k++) b += h1[k]*We3[k*128+t];
  split_store(b, nh, nl, (size_t)nid*128+t);
}

__global__ __launch_bounds__(256) void geom_k(const float* __restrict__ pos,
  const int* __restrict__ ii, const int* __restrict__ jj,
  float* __restrict__ unitv, u16* __restrict__ eh, u16* __restrict__ el){
  int t = threadIdx.x; int e = blockIdx.x*2 + (t>>7); int col = t&127;
  int a = ii[e], b = jj[e];
  float dx = pos[a*3]-pos[b*3], dy=pos[a*3+1]-pos[b*3+1], dz=pos[a*3+2]-pos[b*3+2];
  float dist = sqrtf(dx*dx+dy*dy+dz*dz);
  if (col==0){ float inv=1.f/dist; unitv[e*3]=dx*inv; unitv[e*3+1]=dy*inv; unitv[e*3+2]=dz*inv; }
  const float step = 5.0f/127.0f;
  const float coeff = -0.5f/(step*step);
  float d = dist - step*(float)col;
  float g = __expf(coeff*d*d);
  split_store(g, eh, el, (size_t)e*128+col);
}

__global__ __launch_bounds__(256) void colstats128(const float* __restrict__ m, int M, float* __restrict__ st){
  __shared__ float ls[128], lq[128];
  int t=threadIdx.x; if(t<128){ls[t]=0.f;lq[t]=0.f;} __syncthreads();
  int col=t&127, hf=t>>7; float ps=0.f,pq=0.f;
  int npair=(M+1)>>1;
  for (int pr=blockIdx.x; pr<npair; pr+=gridDim.x){
    int row=pr*2+hf;
    if(row<M){ float v=m[(size_t)row*128+col]; ps+=v; pq+=v*v; }
  }
  atomicAdd(&ls[col],ps); atomicAdd(&lq[col],pq);
  __syncthreads();
  if(t<128){ atomicAdd(&st[t],ls[t]); atomicAdd(&st[128+t],lq[t]); }
}

__global__ __launch_bounds__(256) void node_update_k(u16* __restrict__ nh, u16* __restrict__ nl,
  const float* __restrict__ agg, const float* __restrict__ st,
  const float* __restrict__ g, const float* __restrict__ b, float inv, int Nn)
{
  int t=threadIdx.x; int col=t&127, hf=t>>7;
  float mean = st[col]*inv;
  float var  = st[128+col]*inv - mean*mean;
  float A = g[col]*rsqrtf(var+1e-5f);
  float C = b[col] - A*mean;
  int npair=(Nn+1)>>1;
  for (int pr=blockIdx.x; pr<npair; pr+=gridDim.x){
    int row=pr*2+hf; if(row>=Nn) continue;
    size_t o=(size_t)row*128+col;
    float nv = b2f(nh[o]) + b2f(nl[o]);
    float v = tanhf_(nv + A*agg[o] + C);
    split_store(v, nh, nl, o);
  }
}

__global__ __launch_bounds__(256) void force_k(const u16* __restrict__ fh, const u16* __restrict__ fl,
  const float* __restrict__ Wf3, const float* __restrict__ bf3,
  const float* __restrict__ unitv, const int* __restrict__ ii, float* __restrict__ outp, int Me)
{
  int wv=threadIdx.x>>6, lane=threadIdx.x&63;
  int e = blockIdx.x*4 + wv; if(e>=Me) return;
  size_t o0=(size_t)e*128+lane, o1=o0+64;
  float p = (b2f(fh[o0])+b2f(fl[o0]))*Wf3[lane] + (b2f(fh[o1])+b2f(fl[o1]))*Wf3[64+lane];
  for (int s=32;s>0;s>>=1) p += __shfl_down(p, s);
  if (lane==0){
    float F = p + bf3[0];
    atomicAdd(&outp[ii[e]*3+0], F*unitv[e*3+0]);
    atomicAdd(&outp[ii[e]*3+1], F*unitv[e*3+1]);
    atomicAdd(&outp[ii[e]*3+2], F*unitv[e*3+2]);
  }
}

__global__ void sentinel_k(float* o, int n, float v){
  int i = blockIdx.x*256 + threadIdx.x; if (i<n) o[i]=v;
}

extern "C" void kernel_launch(void* const* d_in, const int* in_sizes, int n_in,
                              void* d_out, int out_size, void* d_ws, size_t ws_size,
                              hipStream_t stream)
{
  (void)in_sizes; (void)n_in;
  const int* z      = (const int*)d_in[0];
  const float* pos  = (const float*)d_in[1];
  const int* ii     = (const int*)d_in[2];
  const int* jj     = (const int*)d_in[3];
  const int* idx_i  = (const int*)d_in[4];
  const int* idx_j  = (const int*)d_in[5];
  const int* idx_k  = (const int*)d_in[6];
  const int* idx_ji = (const int*)d_in[7];
  const int* idx_kj = (const int*)d_in[8];
  const float* We1=(const float*)d_in[9];  const float* be1=(const float*)d_in[10];
  const float* We2=(const float*)d_in[11]; const float* be2=(const float*)d_in[12];
  const float* We3=(const float*)d_in[13]; const float* be3=(const float*)d_in[14];
  const float* Wc1=(const float*)d_in[15]; const float* bc1=(const float*)d_in[16];
  const float* g_c1=(const float*)d_in[17]; const float* b_c1=(const float*)d_in[18];
  const float* g_n=(const float*)d_in[19]; const float* b_n=(const float*)d_in[20];
  const float* Wc2=(const float*)d_in[21]; const float* bc2=(const float*)d_in[22];
  const float* g_c2=(const float*)d_in[23]; const float* b_c2=(const float*)d_in[24];
  const float* Wc3=(const float*)d_in[25]; const float* bc3=(const float*)d_in[26];
  const float* g_c3=(const float*)d_in[27]; const float* b_c3=(const float*)d_in[28];
  const float* g_c22=(const float*)d_in[29]; const float* b_c22=(const float*)d_in[30];
  const float* g_c32=(const float*)d_in[31]; const float* b_c32=(const float*)d_in[32];
  const float* Wf1=(const float*)d_in[33]; const float* bf1=(const float*)d_in[34];
  const float* Wf2=(const float*)d_in[35]; const float* bf2=(const float*)d_in[36];
  const float* Wf3=(const float*)d_in[37]; const float* bf3=(const float*)d_in[38];

  char* ws = (char*)d_ws;
  size_t off=0;
  auto alloc=[&](size_t bb){ size_t o=off; off += (bb+255)&~(size_t)255; return o; };
  u16*   node_h = (u16*)(ws + alloc((size_t)NN*128*2));
  u16*   node_l = (u16*)(ws + alloc((size_t)NN*128*2));
  u16*   edge_h = (u16*)(ws + alloc((size_t)EGN*128*2));
  u16*   edge_l = (u16*)(ws + alloc((size_t)EGN*128*2));
  float* unitv  = (float*)(ws + alloc((size_t)EGN*3*4));
  float* agg    = (float*)(ws + alloc((size_t)NN*128*4));
  float* agg3   = (float*)(ws + alloc((size_t)EGN*128*4));   // reused as f1 planes later
  u16*   wc1h   = (u16*)(ws + alloc((size_t)3*256*256*2));
  u16*   wc1l   = (u16*)(ws + alloc((size_t)3*256*256*2));
  u16*   wc2h   = (u16*)(ws + alloc((size_t)3*256*128*2));
  u16*   wc2l   = (u16*)(ws + alloc((size_t)3*256*128*2));
  u16*   wc3h   = (u16*)(ws + alloc((size_t)3*256*640*2));
  u16*   wc3l   = (u16*)(ws + alloc((size_t)3*256*640*2));
  u16*   wf1h   = (u16*)(ws + alloc((size_t)128*128*2));
  u16*   wf1l   = (u16*)(ws + alloc((size_t)128*128*2));
  u16*   wf2h   = (u16*)(ws + alloc((size_t)128*128*2));
  u16*   wf2l   = (u16*)(ws + alloc((size_t)128*128*2));
  float* stats  = (float*)(ws + alloc(2304*4));

  if (off > ws_size){
    sentinel_k<<<(out_size+255)/256, 256, 0, stream>>>((float*)d_out, out_size, 123456.0f);
    return;
  }

  float* st1 = stats;          // 512 (256 cols)
  float* st2 = stats+512;      // 512
  float* st3 = stats+1024;     // 512
  float* stN = stats+1536;     // 256 (128 cols)
  float* st32= stats+1792;     // 256
  float* st22= stats+2048;     // 256

  u16* f1h = (u16*)agg3;
  u16* f1l = f1h + (size_t)EGN*128;
  u16* f2h = edge_h;
  u16* f2l = edge_l;

  hipMemsetAsync(d_out, 0, (size_t)out_size*4, stream);

  dim3 tb(32,8);
  transpose_cvt<<<dim3(8,8,3),  tb, 0, stream>>>(Wc1, wc1h, wc1l, 256, 256);
  transpose_cvt<<<dim3(8,4,3),  tb, 0, stream>>>(Wc2, wc2h, wc2l, 128, 256);
  transpose_cvt<<<dim3(8,20,3), tb, 0, stream>>>(Wc3, wc3h, wc3l, 640, 256);
  transpose_cvt<<<dim3(4,4,1),  tb, 0, stream>>>(Wf1, wf1h, wf1l, 128, 128);
  transpose_cvt<<<dim3(4,4,1),  tb, 0, stream>>>(Wf2, wf2h, wf2l, 128, 128);

  embed_k<<<NN,128,0,stream>>>(z, We1,be1,We2,be2,We3,be3, node_h, node_l);
  geom_k<<<EGN/2,256,0,stream>>>(pos, ii, jj, unitv, edge_h, edge_l);

  const int gE64  = (EGN+63)/64;    // 3125
  const int gT64  = (TTN+63)/64;    // 4688
  Segs dummy{};
  const float invE = 1.0f/EGN, invT = 1.0f/TTN, invN = 1.0f/NN;

  for (int l=0;l<LLN;l++){
    hipMemsetAsync(stats, 0, 2304*4, stream);
    hipMemsetAsync(agg,  0, (size_t)NN*128*4, stream);
    hipMemsetAsync(agg3, 0, (size_t)EGN*128*4, stream);

    const u16* w1h = wc1h + l*256*256; const u16* w1l = wc1l + l*256*256;
    const u16* w2h = wc2h + l*256*128; const u16* w2l = wc2l + l*256*128;
    const u16* w3h = wc3h + l*256*640; const u16* w3l = wc3l + l*256*640;

    // ---- NodeUpdate: c1 (sources: node[ii], edge) ----
    Segs s1{};
    s1.sh[0]=node_h; s1.sl[0]=node_l; s1.idx[0]=ii;
    s1.sh[1]=edge_h; s1.sl[1]=edge_l; s1.idx[1]=nullptr;
    gemm_stats<2,false><<<gE64,256,0,stream>>>(EGN, s1, nullptr,nullptr,nullptr,nullptr,
                                               w1h, bc1+l*256, st1);
    gemm_pair<2,2,false,0><<<dim3(gE64,2),256,0,stream>>>(EGN, s1, nullptr,nullptr,nullptr,nullptr,
        w1h, w1l, bc1+l*256,
        st1, g_c1+l*256, b_c1+l*256, invE,
        ii, agg,
        nullptr,nullptr,nullptr, nullptr,nullptr,nullptr, 0.f,
        nullptr, nullptr, nullptr, nullptr);
    colstats128<<<256,256,0,stream>>>(agg, NN, stN);
    node_update_k<<<2048,256,0,stream>>>(node_h, node_l, agg, stN, g_n+l*128, b_n+l*128, invN, NN);

    // ---- EdgeUpdate triplet term: c3 (sources: node[i], node[j], node[k], edge[ji], edge[kj]) ----
    Segs s3{};
    s3.sh[0]=node_h; s3.sl[0]=node_l; s3.idx[0]=idx_i;
    s3.sh[1]=node_h; s3.sl[1]=node_l; s3.idx[1]=idx_j;
    s3.sh[2]=node_h; s3.sl[2]=node_l; s3.idx[2]=idx_k;
    s3.sh[3]=edge_h; s3.sl[3]=edge_l; s3.idx[3]=idx_ji;
    s3.sh[4]=edge_h; s3.sl[4]=edge_l; s3.idx[4]=idx_kj;
    gemm_stats<5,false><<<gT64,256,0,stream>>>(TTN, s3, nullptr,nullptr,nullptr,nullptr,
                                               w3h, bc3+l*256, st3);
    gemm_pair<5,2,false,0><<<dim3(gT64,2),256,0,stream>>>(TTN, s3, nullptr,nullptr,nullptr,nullptr,
        w3h, w3l, bc3+l*256,
        st3, g_c3+l*256, b_c3+l*256, invT,
        idx_ji, agg3,
        nullptr,nullptr,nullptr, nullptr,nullptr,nullptr, 0.f,
        nullptr, nullptr, nullptr, nullptr);
    colstats128<<<1024,256,0,stream>>>(agg3, EGN, st32);

    // ---- EdgeUpdate pair term: c2 (prod built on the fly) ----
    gemm_stats<1,true><<<gE64,256,0,stream>>>(EGN, dummy, node_h,node_l,ii,jj,
                                              w2h, bc2+l*256, st2);
    gemm_pair<1,1,true,2><<<dim3(gE64,2),256,0,stream>>>(EGN, dummy, node_h,node_l,ii,jj,
        w2h, nullptr, bc2+l*256,
        st2, g_c2+l*256, b_c2+l*256, invE,
        nullptr, nullptr,
        nullptr,nullptr,nullptr, nullptr,nullptr,nullptr, 0.f,
        nullptr, nullptr, nullptr, st22);
    gemm_pair<1,2,true,1><<<dim3(gE64,2),256,0,stream>>>(EGN, dummy, node_h,node_l,ii,jj,
        w2h, w2l, bc2+l*256,
        st2, g_c2+l*256, b_c2+l*256, invE,
        nullptr, nullptr,
        st22, g_c22+l*128, b_c22+l*128, st32, g_c32+l*128, b_c32+l*128, invE,
        agg3, edge_h, edge_l, nullptr);
  }

  // ---- ForcePredictor ----
  gemm_force<<<gE64,256,0,stream>>>(EGN, edge_h, edge_l, wf1h, wf1l, bf1, f1h, f1l);
  gemm_force<<<gE64,256,0,stream>>>(EGN, f1h, f1l, wf2h, wf2l, bf2, f2h, f2l);
  force_k<<<(EGN+3)/4,256,0,stream>>>(f2h, f2l, Wf3, bf3, unitv, ii, (float*)d_out, EGN);
}

// Round 17
// 4174.127 us; speedup vs baseline: 2.0460x; 2.0460x over previous
//
#include <hip/hip_runtime.h>

typedef unsigned short u16;
typedef unsigned int   u32;
typedef __attribute__((ext_vector_type(8))) short short8;
typedef __attribute__((ext_vector_type(4))) float f32x4;

#define NN  10000
#define EGN 200000
#define TTN 300000
#define LLN 3

__device__ __forceinline__ float b2f(u16 u){ union{u32 i; float f;} x; x.i=(u32)u<<16; return x.f; }
__device__ __forceinline__ u16 f2b(float f){ union{float f; u32 u;} x; x.f=f; u32 r=(x.u + 0x7fffu + ((x.u>>16)&1u))>>16; return (u16)r; }
__device__ __forceinline__ float sigf(float x){ return 1.f/(1.f+__expf(-x)); }
__device__ __forceinline__ float tanhf_(float x){ float e=__expf(2.f*x); return 1.f - 2.f/(e+1.f); }
__device__ __forceinline__ float sspf(float x){ return fmaxf(x,0.f) + log1pf(__expf(-fabsf(x))) - 0.6931471805599453f; }

__device__ __forceinline__ void async16(void* lds, const void* g){
  __builtin_amdgcn_global_load_lds((const __attribute__((address_space(1))) void*)g,
                                   (__attribute__((address_space(3))) void*)lds, 16, 0, 0);
}
__device__ __forceinline__ void split_store(float v, u16* ph, u16* pl, size_t o){
  u16 h = f2b(v); ph[o] = h; pl[o] = f2b(v - b2f(h));
}
__device__ __forceinline__ short8 ldfrag(const u16* P, int row, int kk, int lane){
  int kg = kk*4 + (lane>>4);
  int slot = kg ^ (row&7);
  return *(const short8*)(P + row*64 + slot*8);
}

struct Segs {
  const u16* sh[10];
  const u16* sl[10];
  const int* idx[10];
  int coff[10];          // byte offset within 256B source row (0 or 128)
};

// ---------- staging helpers ----------
template<int NP, int ROWS>
__device__ __forceinline__ void stageA(u16* Ah, u16* Al,
    const u16* sh, const u16* sl, const int* idxp, int coff,
    int rb, int M, int tid){
#pragma unroll
  for (int rnd=0; rnd<ROWS/32; ++rnd){
    int u = rnd*256 + tid;            // ROWS x 8 slots
    int row = u>>3, s = u&7, sw = s ^ (row&7);
    int grow = rb + row; if (grow >= M) grow = M-1;
    int srow = idxp ? idxp[grow] : grow;
    size_t go = (size_t)srow*256 + coff + sw*16;
    async16(Ah + u*8, (const char*)sh + go);
    if (NP==2) async16(Al + u*8, (const char*)sl + go);
  }
}

template<int NP, int ROWS>
__device__ __forceinline__ void stageA_prod(u16* Ah, u16* Al,
    const u16* nh, const u16* nl, const int* pii, const int* pjj,
    int rb, int M, int ks, int tid){
#pragma unroll
  for (int rep=0; rep<ROWS/64; ++rep){
    int row = rep*64 + (tid>>2), q = tid&3;   // 64 rows x 4 quarters (16 cols)
    int e = rb + row; if (e >= M) e = M-1;
    int ia = pii[e], ja = pjj[e];
    const u16* phi = nh + (size_t)ia*128 + ks*64 + q*16;
    const u16* pli = nl + (size_t)ia*128 + ks*64 + q*16;
    const u16* phj = nh + (size_t)ja*128 + ks*64 + q*16;
    const u16* plj = nl + (size_t)ja*128 + ks*64 + q*16;
#pragma unroll
    for (int c=0;c<2;c++){
      short8 hi = *(const short8*)(phi + c*8);
      short8 li = *(const short8*)(pli + c*8);
      short8 hj = *(const short8*)(phj + c*8);
      short8 lj = *(const short8*)(plj + c*8);
      short8 vh, vl;
#pragma unroll
      for (int k=0;k<8;k++){
        float a = b2f((u16)hi[k]) + b2f((u16)li[k]);
        float b = b2f((u16)hj[k]) + b2f((u16)lj[k]);
        float v = a*b;
        u16 h = f2b(v);
        vh[k] = (short)h;
        vl[k] = (short)f2b(v - b2f(h));
      }
      int g = q*2 + c, slot = g ^ (row&7);
      *(short8*)(Ah + row*64 + slot*8) = vh;
      if (NP==2) *(short8*)(Al + row*64 + slot*8) = vl;
    }
  }
}

// identity-mapped B rows (stats: 256 rows; force: 128 rows)
template<int NP, int BROWS>
__device__ __forceinline__ void stageB_id(u16* Bh, u16* Bl,
    const u16* Wh, const u16* Wl, int K2b, int ksoff, int tid){
#pragma unroll
  for (int rnd=0; rnd<BROWS/32; ++rnd){
    int u = rnd*256 + tid;
    int row = u>>3, s = u&7, sw = s ^ (row&7);
    size_t go = (size_t)row*K2b + ksoff + sw*16;
    async16(Bh + u*8, (const char*)Wh + go);
    if (NP==2) async16(Bl + u*8, (const char*)Wl + go);
  }
}

// pair-mapped B rows: LDS rows 0..63 -> W^T rows P0.., rows 64..127 -> W^T rows 128+P0..
template<int NP>
__device__ __forceinline__ void stageB_pair(u16* Bh, u16* Bl,
    const u16* Wh, const u16* Wl, int P0, int K2b, int ksoff, int tid){
#pragma unroll
  for (int rnd=0; rnd<4; ++rnd){
    int u = rnd*256 + tid;
    int row = u>>3, s = u&7, sw = s ^ (row&7);
    int wr = (row < 64) ? (P0 + row) : (128 + P0 + (row-64));
    size_t go = (size_t)wr*K2b + ksoff + sw*16;
    async16(Bh + u*8, (const char*)Wh + go);
    if (NP==2) async16(Bl + u*8, (const char*)Wl + go);
  }
}

// ---------- K1: stats-only GEMM (1 bf16 plane). 64 rows x ALL 256 cols ----------
// wave w owns cols w*64..w*64+63 (4 n-frags) x all 64 rows (4 m-frags): B read once per wave.
template<bool PROD>
__global__ __launch_bounds__(256) void gemm_stats(
  int M, int nseg, Segs segs,
  const u16* __restrict__ nh, const u16* __restrict__ nl,
  const int* __restrict__ pii, const int* __restrict__ pjj,
  const u16* __restrict__ Wh, int K2b, const float* __restrict__ bias,
  float* __restrict__ st)
{
  __shared__ u16 Ah[64*64];        // 8 KB
  __shared__ u16 Bh[256*64];       // 32 KB
  __shared__ float ls[256], lq[256];
  const int tid = threadIdx.x, lane = tid&63, wv = tid>>6;
  const int lane15 = lane&15;
  const int rb = blockIdx.x*64;
  ls[tid]=0.f; lq[tid]=0.f;

  f32x4 acc[4][4];
#pragma unroll
  for (int m=0;m<4;m++)
#pragma unroll
    for (int n=0;n<4;n++) acc[m][n] = (f32x4){0.f,0.f,0.f,0.f};

  for (int ks=0; ks<nseg; ++ks){
    if (PROD) stageA_prod<1,64>(Ah, nullptr, nh, nl, pii, pjj, rb, M, ks, tid);
    else      stageA<1,64>(Ah, nullptr, segs.sh[ks], nullptr, segs.idx[ks], segs.coff[ks], rb, M, tid);
    stageB_id<1,256>(Bh, nullptr, Wh, nullptr, K2b, ks*128, tid);
    __syncthreads();
#pragma unroll
    for (int kk=0;kk<2;kk++){
      short8 a[4];
#pragma unroll
      for (int m=0;m<4;m++) a[m] = ldfrag(Ah, m*16 + lane15, kk, lane);
#pragma unroll
      for (int n=0;n<4;n++){
        short8 b = ldfrag(Bh, wv*64 + n*16 + lane15, kk, lane);
#pragma unroll
        for (int m=0;m<4;m++)
          acc[m][n] = __builtin_amdgcn_mfma_f32_16x16x32_bf16(a[m], b, acc[m][n], 0,0,0);
      }
    }
    __syncthreads();
  }
#pragma unroll
  for (int n=0;n<4;n++){
    int col = wv*64 + n*16 + lane15;
    float bb = bias[col];
    float s=0.f, q=0.f;
#pragma unroll
    for (int m=0;m<4;m++){
#pragma unroll
      for (int r=0;r<4;r++){
        int grow = rb + m*16 + (lane>>4)*4 + r;
        if (grow < M){ float v = acc[m][n][r] + bb; s += v; q += v*v; }
      }
    }
    s += __shfl_xor(s,16); s += __shfl_xor(s,32);
    q += __shfl_xor(q,16); q += __shfl_xor(q,32);
    if (lane < 16){ atomicAdd(&ls[wv*64 + n*16 + lane], s); atomicAdd(&lq[wv*64 + n*16 + lane], q); }
  }
  __syncthreads();
  atomicAdd(&st[tid], ls[tid]); atomicAdd(&st[256+tid], lq[tid]);
}

// ---------- K2: paired GEMM. 64 rows x 64 pairs. wave w owns pairs w*16..+15 x all rows ----------
// EPI 0: scatter sig*tanh into aggout[sidx[row]*128+p]
// EPI 1: edge[row][p] = tanh(edge + BN22(u) + BN32(agg3)) in place
// EPI 2: stats of u -> st22out
template<int NP, bool PROD, int EPI>
__global__ __launch_bounds__(256) void gemm_pair(
  int M, int nseg, Segs segs,
  const u16* __restrict__ nh, const u16* __restrict__ nl,
  const int* __restrict__ pii, const int* __restrict__ pjj,
  const u16* __restrict__ Wh, const u16* __restrict__ Wl, int K2b,
  const float* __restrict__ bias,
  const float* __restrict__ st, const float* __restrict__ g, const float* __restrict__ b, float inv,
  const int* __restrict__ sidx, float* __restrict__ aggout,
  const float* __restrict__ st22, const float* __restrict__ g22, const float* __restrict__ b22,
  const float* __restrict__ st32, const float* __restrict__ g32, const float* __restrict__ b32, float inv2,
  const float* __restrict__ agg3, u16* __restrict__ eh, u16* __restrict__ el,
  float* __restrict__ st22out)
{
  __shared__ u16 Ah[64*64];
  __shared__ u16 Al[NP==2 ? 64*64 : 64];
  __shared__ u16 Bh[128*64];
  __shared__ u16 Bl[NP==2 ? 128*64 : 64];
  __shared__ float ls[64], lq[64];
  __shared__ float sAf[64], sCf[64], sAr[64], sCr[64];
  __shared__ float sA22[64], sC22[64], sA32[64], sC32[64];
  const int tid = threadIdx.x, lane = tid&63, wv = tid>>6;
  const int lane15 = lane&15;
  const int rb = blockIdx.x*64, P0 = blockIdx.y*64;

  if (tid < 64){
    int p = P0 + tid;
    float m1 = st[p]*inv,     v1 = st[256+p]*inv - m1*m1;
    float a1 = g[p]*rsqrtf(v1+1e-5f);
    sAf[tid]=a1; sCf[tid]=b[p]-a1*m1;
    float m2 = st[128+p]*inv, v2 = st[384+p]*inv - m2*m2;
    float a2 = g[128+p]*rsqrtf(v2+1e-5f);
    sAr[tid]=a2; sCr[tid]=b[128+p]-a2*m2;
    if (EPI==1){
      float m3 = st22[p]*inv2, v3 = st22[128+p]*inv2 - m3*m3;
      float a3 = g22[p]*rsqrtf(v3+1e-5f);
      sA22[tid]=a3; sC22[tid]=b22[p]-a3*m3;
      float m4 = st32[p]*inv2, v4 = st32[128+p]*inv2 - m4*m4;
      float a4 = g32[p]*rsqrtf(v4+1e-5f);
      sA32[tid]=a4; sC32[tid]=b32[p]-a4*m4;
    }
    if (EPI==2){ ls[tid]=0.f; lq[tid]=0.f; }
  }

  f32x4 accf[4], accr[4];
#pragma unroll
  for (int m=0;m<4;m++){ accf[m]=(f32x4){0.f,0.f,0.f,0.f}; accr[m]=(f32x4){0.f,0.f,0.f,0.f}; }

  for (int ks=0; ks<nseg; ++ks){
    if (PROD) stageA_prod<NP,64>(Ah, Al, nh, nl, pii, pjj, rb, M, ks, tid);
    else      stageA<NP,64>(Ah, Al, segs.sh[ks], segs.sl[ks], segs.idx[ks], segs.coff[ks], rb, M, tid);
    stageB_pair<NP>(Bh, Bl, Wh, Wl, P0, K2b, ks*128, tid);
    __syncthreads();
#pragma unroll
    for (int kk=0;kk<2;kk++){
      short8 ah[4], al[4];
#pragma unroll
      for (int m=0;m<4;m++){
        ah[m] = ldfrag(Ah, m*16 + lane15, kk, lane);
        if constexpr (NP==2) al[m] = ldfrag(Al, m*16 + lane15, kk, lane);
      }
      short8 bfh = ldfrag(Bh, wv*16 + lane15,      kk, lane);
      short8 brh = ldfrag(Bh, 64 + wv*16 + lane15, kk, lane);
      short8 bfl, brl;
      if constexpr (NP==2){
        bfl = ldfrag(Bl, wv*16 + lane15,      kk, lane);
        brl = ldfrag(Bl, 64 + wv*16 + lane15, kk, lane);
      }
#pragma unroll
      for (int m=0;m<4;m++){
        accf[m] = __builtin_amdgcn_mfma_f32_16x16x32_bf16(ah[m], bfh, accf[m], 0,0,0);
        accr[m] = __builtin_amdgcn_mfma_f32_16x16x32_bf16(ah[m], brh, accr[m], 0,0,0);
        if constexpr (NP==2){
          accf[m] = __builtin_amdgcn_mfma_f32_16x16x32_bf16(ah[m], bfl, accf[m], 0,0,0);
          accf[m] = __builtin_amdgcn_mfma_f32_16x16x32_bf16(al[m], bfh, accf[m], 0,0,0);
          accr[m] = __builtin_amdgcn_mfma_f32_16x16x32_bf16(ah[m], brl, accr[m], 0,0,0);
          accr[m] = __builtin_amdgcn_mfma_f32_16x16x32_bf16(al[m], brh, accr[m], 0,0,0);
        }
      }
    }
    __syncthreads();
  }

  const int pp = wv*16 + lane15;
  const int p  = P0 + pp;
  const float bf_ = bias[p], br_ = bias[128+p];
  const float Af = sAf[pp], Cf = sCf[pp], Ar = sAr[pp], Cr = sCr[pp];
  float su=0.f, sq=0.f;
#pragma unroll
  for (int m=0;m<4;m++){
#pragma unroll
    for (int r=0;r<4;r++){
      int grow = rb + m*16 + (lane>>4)*4 + r;
      if (grow >= M) continue;
      float yf = accf[m][r] + bf_;
      float yr = accr[m][r] + br_;
      float u = sigf(Af*yf + Cf) * tanhf_(Ar*yr + Cr);
      if (EPI==0){
        atomicAdd(&aggout[(size_t)sidx[grow]*128 + p], u);
      } else if (EPI==1){
        size_t o = (size_t)grow*128 + p;
        float eo = b2f(eh[o]) + b2f(el[o]);
        float v = tanhf_(eo + sA22[pp]*u + sC22[pp] + sA32[pp]*agg3[o] + sC32[pp]);
        split_store(v, eh, el, o);
      } else {
        su += u; sq += u*u;
      }
    }
  }
  if (EPI==2){
    su += __shfl_xor(su,16); su += __shfl_xor(su,32);
    sq += __shfl_xor(sq,16); sq += __shfl_xor(sq,32);
    if (lane < 16){ atomicAdd(&ls[wv*16+lane], su); atomicAdd(&lq[wv*16+lane], sq); }
    __syncthreads();
    if (tid < 64){ atomicAdd(&st22out[P0+tid], ls[tid]); atomicAdd(&st22out[128+P0+tid], lq[tid]); }
  }
}

// ---------- K3: force GEMM (split, 64 rows x 128 cols). wave w owns cols w*32..+31 ----------
__global__ __launch_bounds__(256) void gemm_force(
  int M, Segs segs,
  const u16* __restrict__ Wh, const u16* __restrict__ Wl, int K2b,
  const float* __restrict__ bias, u16* __restrict__ oh, u16* __restrict__ ol)
{
  __shared__ u16 Ah[64*64], Al[64*64];
  __shared__ u16 Bh[128*64], Bl[128*64];
  const int tid = threadIdx.x, lane = tid&63, wv = tid>>6;
  const int lane15 = lane&15;
  const int rb = blockIdx.x*64;

  f32x4 acc[4][2];
#pragma unroll
  for (int m=0;m<4;m++)
#pragma unroll
    for (int n=0;n<2;n++) acc[m][n] = (f32x4){0.f,0.f,0.f,0.f};

  for (int ks=0; ks<2; ++ks){
    stageA<2,64>(Ah, Al, segs.sh[ks], segs.sl[ks], segs.idx[ks], segs.coff[ks], rb, M, tid);
    stageB_id<2,128>(Bh, Bl, Wh, Wl, K2b, ks*128, tid);
    __syncthreads();
#pragma unroll
    for (int kk=0;kk<2;kk++){
      short8 ah[4], al[4];
#pragma unroll
      for (int m=0;m<4;m++){
        ah[m] = ldfrag(Ah, m*16 + lane15, kk, lane);
        al[m] = ldfrag(Al, m*16 + lane15, kk, lane);
      }
#pragma unroll
      for (int n=0;n<2;n++){
        short8 bh = ldfrag(Bh, wv*32 + n*16 + lane15, kk, lane);
        short8 bl = ldfrag(Bl, wv*32 + n*16 + lane15, kk, lane);
#pragma unroll
        for (int m=0;m<4;m++){
          acc[m][n] = __builtin_amdgcn_mfma_f32_16x16x32_bf16(ah[m], bh, acc[m][n], 0,0,0);
          acc[m][n] = __builtin_amdgcn_mfma_f32_16x16x32_bf16(ah[m], bl, acc[m][n], 0,0,0);
          acc[m][n] = __builtin_amdgcn_mfma_f32_16x16x32_bf16(al[m], bh, acc[m][n], 0,0,0);
        }
      }
    }
    __syncthreads();
  }
#pragma unroll
  for (int n=0;n<2;n++){
    int col = wv*32 + n*16 + lane15;
    float bb = bias[col];
#pragma unroll
    for (int m=0;m<4;m++){
#pragma unroll
      for (int r=0;r<4;r++){
        int grow = rb + m*16 + (lane>>4)*4 + r;
        if (grow < M){
          float v = sspf(acc[m][n][r] + bb);
          split_store(v, oh, ol, (size_t)grow*128 + col);
        }
      }
    }
  }
}

// ---------- small kernels ----------
__global__ void transpose_cvt(const float* __restrict__ src, u16* __restrict__ dh, u16* __restrict__ dl, int K, int N){
  __shared__ float t[32][33];
  const float* s = src + (size_t)blockIdx.z * K * N;
  u16* dsth = dh + (size_t)blockIdx.z * K * N;
  u16* dstl = dl + (size_t)blockIdx.z * K * N;
  int n0 = blockIdx.x*32, k0 = blockIdx.y*32;
  for (int dy=threadIdx.y; dy<32; dy+=8){
    int k = k0+dy, n = n0+threadIdx.x;
    if (k<K && n<N) t[dy][threadIdx.x] = s[(size_t)k*N + n];
  }
  __syncthreads();
  for (int dy=threadIdx.y; dy<32; dy+=8){
    int n = n0+dy, k = k0+threadIdx.x;
    if (n<N && k<K) split_store(t[threadIdx.x][dy], dsth, dstl, (size_t)n*K + k);
  }
}

__global__ __launch_bounds__(128) void embed_k(const int* __restrict__ z,
  const float* __restrict__ We1, const float* __restrict__ be1,
  const float* __restrict__ We2, const float* __restrict__ be2,
  const float* __restrict__ We3, const float* __restrict__ be3,
  u16* __restrict__ nh, u16* __restrict__ nl){
  __shared__ float h0[128], h1[128];
  int nid = blockIdx.x, t = threadIdx.x;
  int zz = z[nid];
  h0[t] = sspf(We1[zz*128 + t] + be1[t]);
  __syncthreads();
  float a = be2[t];
  for (int k=0;k<128;k++) a += h0[k]*We2[k*128+t];
  h1[t] = sspf(a);
  __syncthreads();
  float b = be3[t];
  for (int k=0;k<128;k++) b += h1[k]*We3[k*128+t];
  split_store(b, nh, nl, (size_t)nid*128+t);
}

__global__ __launch_bounds__(256) void geom_k(const float* __restrict__ pos,
  const int* __restrict__ ii, const int* __restrict__ jj,
  float* __restrict__ unitv, u16* __restrict__ eh, u16* __restrict__ el){
  int t = threadIdx.x; int e = blockIdx.x*2 + (t>>7); int col = t&127;
  int a = ii[e], b = jj[e];
  float dx = pos[a*3]-pos[b*3], dy=pos[a*3+1]-pos[b*3+1], dz=pos[a*3+2]-pos[b*3+2];
  float dist = sqrtf(dx*dx+dy*dy+dz*dz);
  if (col==0){ float inv=1.f/dist; unitv[e*3]=dx*inv; unitv[e*3+1]=dy*inv; unitv[e*3+2]=dz*inv; }
  const float step = 5.0f/127.0f;
  const float coeff = -0.5f/(step*step);
  float d = dist - step*(float)col;
  float g = __expf(coeff*d*d);
  split_store(g, eh, el, (size_t)e*128+col);
}

__global__ __launch_bounds__(256) void colstats128(const float* __restrict__ m, int M, float* __restrict__ st){
  __shared__ float ls[128], lq[128];
  int t=threadIdx.x; if(t<128){ls[t]=0.f;lq[t]=0.f;} __syncthreads();
  int col=t&127, hf=t>>7; float ps=0.f,pq=0.f;
  int npair=(M+1)>>1;
  for (int pr=blockIdx.x; pr<npair; pr+=gridDim.x){
    int row=pr*2+hf;
    if(row<M){ float v=m[(size_t)row*128+col]; ps+=v; pq+=v*v; }
  }
  atomicAdd(&ls[col],ps); atomicAdd(&lq[col],pq);
  __syncthreads();
  if(t<128){ atomicAdd(&st[t],ls[t]); atomicAdd(&st[128+t],lq[t]); }
}

__global__ __launch_bounds__(256) void node_update_k(u16* __restrict__ nh, u16* __restrict__ nl,
  const float* __restrict__ agg, const float* __restrict__ st,
  const float* __restrict__ g, const float* __restrict__ b, float inv, int Nn)
{
  int t=threadIdx.x; int col=t&127, hf=t>>7;
  float mean = st[col]*inv;
  float var  = st[128+col]*inv - mean*mean;
  float A = g[col]*rsqrtf(var+1e-5f);
  float C = b[col] - A*mean;
  int npair=(Nn+1)>>1;
  for (int pr=blockIdx.x; pr<npair; pr+=gridDim.x){
    int row=pr*2+hf; if(row>=Nn) continue;
    size_t o=(size_t)row*128+col;
    float nv = b2f(nh[o]) + b2f(nl[o]);
    float v = tanhf_(nv + A*agg[o] + C);
    split_store(v, nh, nl, o);
  }
}

__global__ __launch_bounds__(256) void force_k(const u16* __restrict__ fh, const u16* __restrict__ fl,
  const float* __restrict__ Wf3, const float* __restrict__ bf3,
  const float* __restrict__ unitv, const int* __restrict__ ii, float* __restrict__ outp, int Me)
{
  int wv=threadIdx.x>>6, lane=threadIdx.x&63;
  int e = blockIdx.x*4 + wv; if(e>=Me) return;
  size_t o0=(size_t)e*128+lane, o1=o0+64;
  float p = (b2f(fh[o0])+b2f(fl[o0]))*Wf3[lane] + (b2f(fh[o1])+b2f(fl[o1]))*Wf3[64+lane];
  for (int s=32;s>0;s>>=1) p += __shfl_down(p, s);
  if (lane==0){
    float F = p + bf3[0];
    atomicAdd(&outp[ii[e]*3+0], F*unitv[e*3+0]);
    atomicAdd(&outp[ii[e]*3+1], F*unitv[e*3+1]);
    atomicAdd(&outp[ii[e]*3+2], F*unitv[e*3+2]);
  }
}

__global__ void sentinel_k(float* o, int n, float v){
  int i = blockIdx.x*256 + threadIdx.x; if (i<n) o[i]=v;
}

extern "C" void kernel_launch(void* const* d_in, const int* in_sizes, int n_in,
                              void* d_out, int out_size, void* d_ws, size_t ws_size,
                              hipStream_t stream)
{
  (void)in_sizes; (void)n_in;
  const int* z      = (const int*)d_in[0];
  const float* pos  = (const float*)d_in[1];
  const int* ii     = (const int*)d_in[2];
  const int* jj     = (const int*)d_in[3];
  const int* idx_i  = (const int*)d_in[4];
  const int* idx_j  = (const int*)d_in[5];
  const int* idx_k  = (const int*)d_in[6];
  const int* idx_ji = (const int*)d_in[7];
  const int* idx_kj = (const int*)d_in[8];
  const float* We1=(const float*)d_in[9];  const float* be1=(const float*)d_in[10];
  const float* We2=(const float*)d_in[11]; const float* be2=(const float*)d_in[12];
  const float* We3=(const float*)d_in[13]; const float* be3=(const float*)d_in[14];
  const float* Wc1=(const float*)d_in[15]; const float* bc1=(const float*)d_in[16];
  const float* g_c1=(const float*)d_in[17]; const float* b_c1=(const float*)d_in[18];
  const float* g_n=(const float*)d_in[19]; const float* b_n=(const float*)d_in[20];
  const float* Wc2=(const float*)d_in[21]; const float* bc2=(const float*)d_in[22];
  const float* g_c2=(const float*)d_in[23]; const float* b_c2=(const float*)d_in[24];
  const float* Wc3=(const float*)d_in[25]; const float* bc3=(const float*)d_in[26];
  const float* g_c3=(const float*)d_in[27]; const float* b_c3=(const float*)d_in[28];
  const float* g_c22=(const float*)d_in[29]; const float* b_c22=(const float*)d_in[30];
  const float* g_c32=(const float*)d_in[31]; const float* b_c32=(const float*)d_in[32];
  const float* Wf1=(const float*)d_in[33]; const float* bf1=(const float*)d_in[34];
  const float* Wf2=(const float*)d_in[35]; const float* bf2=(const float*)d_in[36];
  const float* Wf3=(const float*)d_in[37]; const float* bf3=(const float*)d_in[38];

  char* ws = (char*)d_ws;
  size_t off=0;
  auto alloc=[&](size_t bb){ size_t o=off; off += (bb+255)&~(size_t)255; return o; };
  u16*   node_h = (u16*)(ws + alloc((size_t)NN*128*2));
  u16*   node_l = (u16*)(ws + alloc((size_t)NN*128*2));
  u16*   edge_h = (u16*)(ws + alloc((size_t)EGN*128*2));
  u16*   edge_l = (u16*)(ws + alloc((size_t)EGN*128*2));
  float* unitv  = (float*)(ws + alloc((size_t)EGN*3*4));
  float* agg    = (float*)(ws + alloc((size_t)NN*128*4));
  float* agg3   = (float*)(ws + alloc((size_t)EGN*128*4));   // reused as f1 planes later
  u16*   wc1h   = (u16*)(ws + alloc((size_t)3*256*256*2));
  u16*   wc1l   = (u16*)(ws + alloc((size_t)3*256*256*2));
  u16*   wc2h   = (u16*)(ws + alloc((size_t)3*256*128*2));
  u16*   wc2l   = (u16*)(ws + alloc((size_t)3*256*128*2));
  u16*   wc3h   = (u16*)(ws + alloc((size_t)3*256*640*2));
  u16*   wc3l   = (u16*)(ws + alloc((size_t)3*256*640*2));
  u16*   wf1h   = (u16*)(ws + alloc((size_t)128*128*2));
  u16*   wf1l   = (u16*)(ws + alloc((size_t)128*128*2));
  u16*   wf2h   = (u16*)(ws + alloc((size_t)128*128*2));
  u16*   wf2l   = (u16*)(ws + alloc((size_t)128*128*2));
  float* stats  = (float*)(ws + alloc(2304*4));

  if (off > ws_size){
    sentinel_k<<<(out_size+255)/256, 256, 0, stream>>>((float*)d_out, out_size, 123456.0f);
    return;
  }

  float* st1 = stats;          // 512 (256 cols)
  float* st2 = stats+512;      // 512
  float* st3 = stats+1024;     // 512
  float* stN = stats+1536;     // 256 (128 cols)
  float* st32= stats+1792;     // 256
  float* st22= stats+2048;     // 256

  u16* f1h = (u16*)agg3;
  u16* f1l = f1h + (size_t)EGN*128;
  u16* f2h = edge_h;
  u16* f2l = edge_l;

  hipMemsetAsync(d_out, 0, (size_t)out_size*4, stream);

  dim3 tb(32,8);
  transpose_cvt<<<dim3(8,8,3),  tb, 0, stream>>>(Wc1, wc1h, wc1l, 256, 256);
  transpose_cvt<<<dim3(8,4,3),  tb, 0, stream>>>(Wc2, wc2h, wc2l, 128, 256);
  transpose_cvt<<<dim3(8,20,3), tb, 0, stream>>>(Wc3, wc3h, wc3l, 640, 256);
  transpose_cvt<<<dim3(4,4,1),  tb, 0, stream>>>(Wf1, wf1h, wf1l, 128, 128);
  transpose_cvt<<<dim3(4,4,1),  tb, 0, stream>>>(Wf2, wf2h, wf2l, 128, 128);

  embed_k<<<NN,128,0,stream>>>(z, We1,be1,We2,be2,We3,be3, node_h, node_l);
  geom_k<<<EGN/2,256,0,stream>>>(pos, ii, jj, unitv, edge_h, edge_l);

  const int gE64  = (EGN+63)/64;    // 3125
  const int gT64  = (TTN+63)/64;    // 4688
  Segs dummy{};
  const float invE = 1.0f/EGN, invT = 1.0f/TTN, invN = 1.0f/NN;

  for (int l=0;l<LLN;l++){
    hipMemsetAsync(stats, 0, 2304*4, stream);
    hipMemsetAsync(agg,  0, (size_t)NN*128*4, stream);
    hipMemsetAsync(agg3, 0, (size_t)EGN*128*4, stream);

    const u16* w1h = wc1h + l*256*256; const u16* w1l = wc1l + l*256*256;
    const u16* w2h = wc2h + l*256*128; const u16* w2l = wc2l + l*256*128;
    const u16* w3h = wc3h + l*256*640; const u16* w3l = wc3l + l*256*640;

    // ---- NodeUpdate: c1 ----
    Segs s1{};
    s1.sh[0]=node_h; s1.sl[0]=node_l; s1.idx[0]=ii;      s1.coff[0]=0;
    s1.sh[1]=node_h; s1.sl[1]=node_l; s1.idx[1]=ii;      s1.coff[1]=128;
    s1.sh[2]=edge_h; s1.sl[2]=edge_l; s1.idx[2]=nullptr; s1.coff[2]=0;
    s1.sh[3]=edge_h; s1.sl[3]=edge_l; s1.idx[3]=nullptr; s1.coff[3]=128;
    gemm_stats<false><<<gE64,256,0,stream>>>(EGN, 4, s1, nullptr,nullptr,nullptr,nullptr,
                                             w1h, 512, bc1+l*256, st1);
    gemm_pair<2,false,0><<<dim3(gE64,2),256,0,stream>>>(EGN, 4, s1, nullptr,nullptr,nullptr,nullptr,
        w1h, w1l, 512, bc1+l*256,
        st1, g_c1+l*256, b_c1+l*256, invE,
        ii, agg,
        nullptr,nullptr,nullptr, nullptr,nullptr,nullptr, 0.f,
        nullptr, nullptr, nullptr, nullptr);
    colstats128<<<256,256,0,stream>>>(agg, NN, stN);
    node_update_k<<<2048,256,0,stream>>>(node_h, node_l, agg, stN, g_n+l*128, b_n+l*128, invN, NN);

    // ---- EdgeUpdate triplet term: c3 ----
    Segs s3{};
    s3.sh[0]=node_h; s3.sl[0]=node_l; s3.idx[0]=idx_i;  s3.coff[0]=0;
    s3.sh[1]=node_h; s3.sl[1]=node_l; s3.idx[1]=idx_i;  s3.coff[1]=128;
    s3.sh[2]=node_h; s3.sl[2]=node_l; s3.idx[2]=idx_j;  s3.coff[2]=0;
    s3.sh[3]=node_h; s3.sl[3]=node_l; s3.idx[3]=idx_j;  s3.coff[3]=128;
    s3.sh[4]=node_h; s3.sl[4]=node_l; s3.idx[4]=idx_k;  s3.coff[4]=0;
    s3.sh[5]=node_h; s3.sl[5]=node_l; s3.idx[5]=idx_k;  s3.coff[5]=128;
    s3.sh[6]=edge_h; s3.sl[6]=edge_l; s3.idx[6]=idx_ji; s3.coff[6]=0;
    s3.sh[7]=edge_h; s3.sl[7]=edge_l; s3.idx[7]=idx_ji; s3.coff[7]=128;
    s3.sh[8]=edge_h; s3.sl[8]=edge_l; s3.idx[8]=idx_kj; s3.coff[8]=0;
    s3.sh[9]=edge_h; s3.sl[9]=edge_l; s3.idx[9]=idx_kj; s3.coff[9]=128;
    gemm_stats<false><<<gT64,256,0,stream>>>(TTN, 10, s3, nullptr,nullptr,nullptr,nullptr,
                                             w3h, 1280, bc3+l*256, st3);
    gemm_pair<2,false,0><<<dim3(gT64,2),256,0,stream>>>(TTN, 10, s3, nullptr,nullptr,nullptr,nullptr,
        w3h, w3l, 1280, bc3+l*256,
        st3, g_c3+l*256, b_c3+l*256, invT,
        idx_ji, agg3,
        nullptr,nullptr,nullptr, nullptr,nullptr,nullptr, 0.f,
        nullptr, nullptr, nullptr, nullptr);
    colstats128<<<1024,256,0,stream>>>(agg3, EGN, st32);

    // ---- EdgeUpdate pair term: c2 (prod built on the fly) ----
    gemm_stats<true><<<gE64,256,0,stream>>>(EGN, 2, dummy, node_h,node_l,ii,jj,
                                            w2h, 256, bc2+l*256, st2);
    gemm_pair<1,true,2><<<dim3(gE64,2),256,0,stream>>>(EGN, 2, dummy, node_h,node_l,ii,jj,
        w2h, nullptr, 256, bc2+l*256,
        st2, g_c2+l*256, b_c2+l*256, invE,
        nullptr, nullptr,
        nullptr,nullptr,nullptr, nullptr,nullptr,nullptr, 0.f,
        nullptr, nullptr, nullptr, st22);
    gemm_pair<2,true,1><<<dim3(gE64,2),256,0,stream>>>(EGN, 2, dummy, node_h,node_l,ii,jj,
        w2h, w2l, 256, bc2+l*256,
        st2, g_c2+l*256, b_c2+l*256, invE,
        nullptr, nullptr,
        st22, g_c22+l*128, b_c22+l*128, st32, g_c32+l*128, b_c32+l*128, invE,
        agg3, edge_h, edge_l, nullptr);
  }

  // ---- ForcePredictor ----
  Segs sf1{}; sf1.sh[0]=edge_h; sf1.sl[0]=edge_l; sf1.idx[0]=nullptr; sf1.coff[0]=0;
              sf1.sh[1]=edge_h; sf1.sl[1]=edge_l; sf1.idx[1]=nullptr; sf1.coff[1]=128;
  gemm_force<<<gE64,256,0,stream>>>(EGN, sf1, wf1h, wf1l, 256, bf1, f1h, f1l);
  Segs sf2{}; sf2.sh[0]=f1h; sf2.sl[0]=f1l; sf2.idx[0]=nullptr; sf2.coff[0]=0;
              sf2.sh[1]=f1h; sf2.sl[1]=f1l; sf2.idx[1]=nullptr; sf2.coff[1]=128;
  gemm_force<<<gE64,256,0,stream>>>(EGN, sf2, wf2h, wf2l, 256, bf2, f2h, f2l);
  force_k<<<(EGN+3)/4,256,0,stream>>>(f2h, f2l, Wf3, bf3, unitv, ii, (float*)d_out, EGN);
}

// Round 18
// 4012.238 us; speedup vs baseline: 2.1285x; 1.0403x over previous
//
#include <hip/hip_runtime.h>

typedef unsigned short u16;
typedef unsigned int   u32;
typedef __attribute__((ext_vector_type(8))) short short8;
typedef __attribute__((ext_vector_type(4))) float f32x4;

#define NN  10000
#define EGN 200000
#define TTN 300000
#define LLN 3

__device__ __forceinline__ float b2f(u16 u){ union{u32 i; float f;} x; x.i=(u32)u<<16; return x.f; }
__device__ __forceinline__ u16 f2b(float f){ union{float f; u32 u;} x; x.f=f; u32 r=(x.u + 0x7fffu + ((x.u>>16)&1u))>>16; return (u16)r; }
__device__ __forceinline__ float sigf(float x){ return 1.f/(1.f+__expf(-x)); }
__device__ __forceinline__ float tanhf_(float x){ float e=__expf(2.f*x); return 1.f - 2.f/(e+1.f); }
__device__ __forceinline__ float sspf(float x){ return fmaxf(x,0.f) + log1pf(__expf(-fabsf(x))) - 0.6931471805599453f; }

__device__ __forceinline__ void async16(void* lds, const void* g){
  __builtin_amdgcn_global_load_lds((const __attribute__((address_space(1))) void*)g,
                                   (__attribute__((address_space(3))) void*)lds, 16, 0, 0);
}
__device__ __forceinline__ void split_store(float v, u16* ph, u16* pl, size_t o){
  u16 h = f2b(v); ph[o] = h; pl[o] = f2b(v - b2f(h));
}
__device__ __forceinline__ short8 ldfrag(const u16* P, int row, int kk, int lane){
  int kg = kk*4 + (lane>>4);
  int slot = kg ^ (row&7);
  return *(const short8*)(P + row*64 + slot*8);
}

struct Segs {
  const u16* sh[10];
  const u16* sl[10];
  const int* idx[10];
  int coff[10];          // byte offset within 256B source row (0 or 128)
};

// ---------- staging helpers ----------
template<int NP, int ROWS>
__device__ __forceinline__ void stageA(u16* Ah, u16* Al,
    const u16* sh, const u16* sl, const int* idxp, int coff,
    int rb, int M, int tid){
#pragma unroll
  for (int rnd=0; rnd<ROWS/32; ++rnd){
    int u = rnd*256 + tid;            // ROWS x 8 slots
    int row = u>>3, s = u&7, sw = s ^ (row&7);
    int grow = rb + row; if (grow >= M) grow = M-1;
    int srow = idxp ? idxp[grow] : grow;
    size_t go = (size_t)srow*256 + coff + sw*16;
    async16(Ah + u*8, (const char*)sh + go);
    if (NP==2) async16(Al + u*8, (const char*)sl + go);
  }
}

template<int NP, int ROWS>
__device__ __forceinline__ void stageA_prod(u16* Ah, u16* Al,
    const u16* nh, const u16* nl, const int* pii, const int* pjj,
    int rb, int M, int ks, int tid){
#pragma unroll
  for (int rep=0; rep<ROWS/64; ++rep){
    int row = rep*64 + (tid>>2), q = tid&3;   // 64 rows x 4 quarters (16 cols)
    int e = rb + row; if (e >= M) e = M-1;
    int ia = pii[e], ja = pjj[e];
    const u16* phi = nh + (size_t)ia*128 + ks*64 + q*16;
    const u16* pli = nl + (size_t)ia*128 + ks*64 + q*16;
    const u16* phj = nh + (size_t)ja*128 + ks*64 + q*16;
    const u16* plj = nl + (size_t)ja*128 + ks*64 + q*16;
#pragma unroll
    for (int c=0;c<2;c++){
      short8 hi = *(const short8*)(phi + c*8);
      short8 li = *(const short8*)(pli + c*8);
      short8 hj = *(const short8*)(phj + c*8);
      short8 lj = *(const short8*)(plj + c*8);
      short8 vh, vl;
#pragma unroll
      for (int k=0;k<8;k++){
        float a = b2f((u16)hi[k]) + b2f((u16)li[k]);
        float b = b2f((u16)hj[k]) + b2f((u16)lj[k]);
        float v = a*b;
        u16 h = f2b(v);
        vh[k] = (short)h;
        vl[k] = (short)f2b(v - b2f(h));
      }
      int g = q*2 + c, slot = g ^ (row&7);
      *(short8*)(Ah + row*64 + slot*8) = vh;
      if (NP==2) *(short8*)(Al + row*64 + slot*8) = vl;
    }
  }
}

// identity-mapped B rows (stats: 256 rows; force: 128 rows)
template<int NP, int BROWS>
__device__ __forceinline__ void stageB_id(u16* Bh, u16* Bl,
    const u16* Wh, const u16* Wl, int K2b, int ksoff, int tid){
#pragma unroll
  for (int rnd=0; rnd<BROWS/32; ++rnd){
    int u = rnd*256 + tid;
    int row = u>>3, s = u&7, sw = s ^ (row&7);
    size_t go = (size_t)row*K2b + ksoff + sw*16;
    async16(Bh + u*8, (const char*)Wh + go);
    if (NP==2) async16(Bl + u*8, (const char*)Wl + go);
  }
}

// pair-mapped B rows: LDS rows 0..63 -> W^T rows P0.., rows 64..127 -> W^T rows 128+P0..
template<int NP>
__device__ __forceinline__ void stageB_pair(u16* Bh, u16* Bl,
    const u16* Wh, const u16* Wl, int P0, int K2b, int ksoff, int tid){
#pragma unroll
  for (int rnd=0; rnd<4; ++rnd){
    int u = rnd*256 + tid;
    int row = u>>3, s = u&7, sw = s ^ (row&7);
    int wr = (row < 64) ? (P0 + row) : (128 + P0 + (row-64));
    size_t go = (size_t)wr*K2b + ksoff + sw*16;
    async16(Bh + u*8, (const char*)Wh + go);
    if (NP==2) async16(Bl + u*8, (const char*)Wl + go);
  }
}

// ---------- K1: stats-only GEMM (1 bf16 plane). 64 rows x ALL 256 cols ----------
template<bool PROD>
__global__ __launch_bounds__(256) void gemm_stats(
  int M, int nseg, Segs segs,
  const u16* __restrict__ nh, const u16* __restrict__ nl,
  const int* __restrict__ pii, const int* __restrict__ pjj,
  const u16* __restrict__ Wh, int K2b, const float* __restrict__ bias,
  float* __restrict__ st)
{
  __shared__ u16 Ah[64*64];        // 8 KB
  __shared__ u16 Bh[256*64];       // 32 KB
  __shared__ float ls[256], lq[256];
  const int tid = threadIdx.x, lane = tid&63, wv = tid>>6;
  const int lane15 = lane&15;
  const int rb = blockIdx.x*64;
  ls[tid]=0.f; lq[tid]=0.f;

  f32x4 acc[4][4];
#pragma unroll
  for (int m=0;m<4;m++)
#pragma unroll
    for (int n=0;n<4;n++) acc[m][n] = (f32x4){0.f,0.f,0.f,0.f};

  for (int ks=0; ks<nseg; ++ks){
    if (PROD) stageA_prod<1,64>(Ah, nullptr, nh, nl, pii, pjj, rb, M, ks, tid);
    else      stageA<1,64>(Ah, nullptr, segs.sh[ks], nullptr, segs.idx[ks], segs.coff[ks], rb, M, tid);
    stageB_id<1,256>(Bh, nullptr, Wh, nullptr, K2b, ks*128, tid);
    __syncthreads();
#pragma unroll
    for (int kk=0;kk<2;kk++){
      short8 a[4];
#pragma unroll
      for (int m=0;m<4;m++) a[m] = ldfrag(Ah, m*16 + lane15, kk, lane);
#pragma unroll
      for (int n=0;n<4;n++){
        short8 b = ldfrag(Bh, wv*64 + n*16 + lane15, kk, lane);
#pragma unroll
        for (int m=0;m<4;m++)
          acc[m][n] = __builtin_amdgcn_mfma_f32_16x16x32_bf16(a[m], b, acc[m][n], 0,0,0);
      }
    }
    __syncthreads();
  }
#pragma unroll
  for (int n=0;n<4;n++){
    int col = wv*64 + n*16 + lane15;
    float bb = bias[col];
    float s=0.f, q=0.f;
#pragma unroll
    for (int m=0;m<4;m++){
#pragma unroll
      for (int r=0;r<4;r++){
        int grow = rb + m*16 + (lane>>4)*4 + r;
        if (grow < M){ float v = acc[m][n][r] + bb; s += v; q += v*v; }
      }
    }
    s += __shfl_xor(s,16); s += __shfl_xor(s,32);
    q += __shfl_xor(q,16); q += __shfl_xor(q,32);
    if (lane < 16){ atomicAdd(&ls[wv*64 + n*16 + lane], s); atomicAdd(&lq[wv*64 + n*16 + lane], q); }
  }
  __syncthreads();
  atomicAdd(&st[tid], ls[tid]); atomicAdd(&st[256+tid], lq[tid]);
}

// ---------- K2: paired GEMM, MERGED halves. 64 rows x ALL 128 pairs; A staged once/K-step ----------
// EPI 0: scatter sig*tanh into aggout[sidx[row]*128+p]
// EPI 1: edge[row][p] = tanh(edge + BN22(u) + BN32(agg3)) in place
// EPI 2: stats of u -> st22out
template<int NP, bool PROD, int EPI>
__global__ __launch_bounds__(256) void gemm_pair(
  int M, int nseg, Segs segs,
  const u16* __restrict__ nh, const u16* __restrict__ nl,
  const int* __restrict__ pii, const int* __restrict__ pjj,
  const u16* __restrict__ Wh, const u16* __restrict__ Wl, int K2b,
  const float* __restrict__ bias,
  const float* __restrict__ st, const float* __restrict__ g, const float* __restrict__ b, float inv,
  const int* __restrict__ sidx, float* __restrict__ aggout,
  const float* __restrict__ st22, const float* __restrict__ g22, const float* __restrict__ b22,
  const float* __restrict__ st32, const float* __restrict__ g32, const float* __restrict__ b32, float inv2,
  const float* __restrict__ agg3, u16* __restrict__ eh, u16* __restrict__ el,
  float* __restrict__ st22out)
{
  __shared__ u16 Ah[64*64];
  __shared__ u16 Al[NP==2 ? 64*64 : 64];
  __shared__ u16 Bh[128*64];
  __shared__ u16 Bl[NP==2 ? 128*64 : 64];
  __shared__ float ls[EPI==2 ? 128 : 1], lq[EPI==2 ? 128 : 1];
  __shared__ float sAf[128], sCf[128], sAr[128], sCr[128];
  __shared__ float sA22[EPI==1 ? 128 : 1], sC22[EPI==1 ? 128 : 1];
  __shared__ float sA32[EPI==1 ? 128 : 1], sC32[EPI==1 ? 128 : 1];
  const int tid = threadIdx.x, lane = tid&63, wv = tid>>6;
  const int lane15 = lane&15;
  const int rb = blockIdx.x*64;

  if (tid < 128){
    int p = tid;
    float m1 = st[p]*inv,     v1 = st[256+p]*inv - m1*m1;
    float a1 = g[p]*rsqrtf(v1+1e-5f);
    sAf[tid]=a1; sCf[tid]=b[p]-a1*m1;
    float m2 = st[128+p]*inv, v2 = st[384+p]*inv - m2*m2;
    float a2 = g[128+p]*rsqrtf(v2+1e-5f);
    sAr[tid]=a2; sCr[tid]=b[128+p]-a2*m2;
    if (EPI==1){
      float m3 = st22[p]*inv2, v3 = st22[128+p]*inv2 - m3*m3;
      float a3 = g22[p]*rsqrtf(v3+1e-5f);
      sA22[tid]=a3; sC22[tid]=b22[p]-a3*m3;
      float m4 = st32[p]*inv2, v4 = st32[128+p]*inv2 - m4*m4;
      float a4 = g32[p]*rsqrtf(v4+1e-5f);
      sA32[tid]=a4; sC32[tid]=b32[p]-a4*m4;
    }
    if (EPI==2){ ls[tid]=0.f; lq[tid]=0.f; }
  }

  f32x4 accf[2][4], accr[2][4];
#pragma unroll
  for (int h=0;h<2;h++)
#pragma unroll
    for (int m=0;m<4;m++){ accf[h][m]=(f32x4){0.f,0.f,0.f,0.f}; accr[h][m]=(f32x4){0.f,0.f,0.f,0.f}; }

  for (int ks=0; ks<nseg; ++ks){
    // stage A once per K-step (gathered, HBM-expensive)
    if (PROD) stageA_prod<NP,64>(Ah, Al, nh, nl, pii, pjj, rb, M, ks, tid);
    else      stageA<NP,64>(Ah, Al, segs.sh[ks], segs.sl[ks], segs.idx[ks], segs.coff[ks], rb, M, tid);
#pragma unroll
    for (int h=0;h<2;h++){
      // stage B for this half (L2-resident weights)
      stageB_pair<NP>(Bh, Bl, Wh, Wl, h*64, K2b, ks*128, tid);
      __syncthreads();
#pragma unroll
      for (int kk=0;kk<2;kk++){
        short8 ah[4], al[4];
#pragma unroll
        for (int m=0;m<4;m++){
          ah[m] = ldfrag(Ah, m*16 + lane15, kk, lane);
          if constexpr (NP==2) al[m] = ldfrag(Al, m*16 + lane15, kk, lane);
        }
        short8 bfh = ldfrag(Bh, wv*16 + lane15,      kk, lane);
        short8 brh = ldfrag(Bh, 64 + wv*16 + lane15, kk, lane);
        short8 bfl, brl;
        if constexpr (NP==2){
          bfl = ldfrag(Bl, wv*16 + lane15,      kk, lane);
          brl = ldfrag(Bl, 64 + wv*16 + lane15, kk, lane);
        }
#pragma unroll
        for (int m=0;m<4;m++){
          accf[h][m] = __builtin_amdgcn_mfma_f32_16x16x32_bf16(ah[m], bfh, accf[h][m], 0,0,0);
          accr[h][m] = __builtin_amdgcn_mfma_f32_16x16x32_bf16(ah[m], brh, accr[h][m], 0,0,0);
          if constexpr (NP==2){
            accf[h][m] = __builtin_amdgcn_mfma_f32_16x16x32_bf16(ah[m], bfl, accf[h][m], 0,0,0);
            accf[h][m] = __builtin_amdgcn_mfma_f32_16x16x32_bf16(al[m], bfh, accf[h][m], 0,0,0);
            accr[h][m] = __builtin_amdgcn_mfma_f32_16x16x32_bf16(ah[m], brl, accr[h][m], 0,0,0);
            accr[h][m] = __builtin_amdgcn_mfma_f32_16x16x32_bf16(al[m], brh, accr[h][m], 0,0,0);
          }
        }
      }
      __syncthreads();   // all reads done before restaging B (or A next ks)
    }
  }

#pragma unroll
  for (int h=0;h<2;h++){
    const int pp = h*64 + wv*16 + lane15;   // global pair 0..127
    const float bf_ = bias[pp], br_ = bias[128+pp];
    const float Af = sAf[pp], Cf = sCf[pp], Ar = sAr[pp], Cr = sCr[pp];
    float su=0.f, sq=0.f;
#pragma unroll
    for (int m=0;m<4;m++){
#pragma unroll
      for (int r=0;r<4;r++){
        int grow = rb + m*16 + (lane>>4)*4 + r;
        if (grow >= M) continue;
        float yf = accf[h][m][r] + bf_;
        float yr = accr[h][m][r] + br_;
        float u = sigf(Af*yf + Cf) * tanhf_(Ar*yr + Cr);
        if (EPI==0){
          atomicAdd(&aggout[(size_t)sidx[grow]*128 + pp], u);
        } else if (EPI==1){
          size_t o = (size_t)grow*128 + pp;
          float eo = b2f(eh[o]) + b2f(el[o]);
          float v = tanhf_(eo + sA22[pp]*u + sC22[pp] + sA32[pp]*agg3[o] + sC32[pp]);
          split_store(v, eh, el, o);
        } else {
          su += u; sq += u*u;
        }
      }
    }
    if (EPI==2){
      su += __shfl_xor(su,16); su += __shfl_xor(su,32);
      sq += __shfl_xor(sq,16); sq += __shfl_xor(sq,32);
      if (lane < 16){ atomicAdd(&ls[h*64 + wv*16 + lane], su); atomicAdd(&lq[h*64 + wv*16 + lane], sq); }
    }
  }
  if (EPI==2){
    __syncthreads();
    if (tid < 128){ atomicAdd(&st22out[tid], ls[tid]); atomicAdd(&st22out[128+tid], lq[tid]); }
  }
}

// ---------- K3: force GEMM (split, 64 rows x 128 cols). wave w owns cols w*32..+31 ----------
__global__ __launch_bounds__(256) void gemm_force(
  int M, Segs segs,
  const u16* __restrict__ Wh, const u16* __restrict__ Wl, int K2b,
  const float* __restrict__ bias, u16* __restrict__ oh, u16* __restrict__ ol)
{
  __shared__ u16 Ah[64*64], Al[64*64];
  __shared__ u16 Bh[128*64], Bl[128*64];
  const int tid = threadIdx.x, lane = tid&63, wv = tid>>6;
  const int lane15 = lane&15;
  const int rb = blockIdx.x*64;

  f32x4 acc[4][2];
#pragma unroll
  for (int m=0;m<4;m++)
#pragma unroll
    for (int n=0;n<2;n++) acc[m][n] = (f32x4){0.f,0.f,0.f,0.f};

  for (int ks=0; ks<2; ++ks){
    stageA<2,64>(Ah, Al, segs.sh[ks], segs.sl[ks], segs.idx[ks], segs.coff[ks], rb, M, tid);
    stageB_id<2,128>(Bh, Bl, Wh, Wl, K2b, ks*128, tid);
    __syncthreads();
#pragma unroll
    for (int kk=0;kk<2;kk++){
      short8 ah[4], al[4];
#pragma unroll
      for (int m=0;m<4;m++){
        ah[m] = ldfrag(Ah, m*16 + lane15, kk, lane);
        al[m] = ldfrag(Al, m*16 + lane15, kk, lane);
      }
#pragma unroll
      for (int n=0;n<2;n++){
        short8 bh = ldfrag(Bh, wv*32 + n*16 + lane15, kk, lane);
        short8 bl = ldfrag(Bl, wv*32 + n*16 + lane15, kk, lane);
#pragma unroll
        for (int m=0;m<4;m++){
          acc[m][n] = __builtin_amdgcn_mfma_f32_16x16x32_bf16(ah[m], bh, acc[m][n], 0,0,0);
          acc[m][n] = __builtin_amdgcn_mfma_f32_16x16x32_bf16(ah[m], bl, acc[m][n], 0,0,0);
          acc[m][n] = __builtin_amdgcn_mfma_f32_16x16x32_bf16(al[m], bh, acc[m][n], 0,0,0);
        }
      }
    }
    __syncthreads();
  }
#pragma unroll
  for (int n=0;n<2;n++){
    int col = wv*32 + n*16 + lane15;
    float bb = bias[col];
#pragma unroll
    for (int m=0;m<4;m++){
#pragma unroll
      for (int r=0;r<4;r++){
        int grow = rb + m*16 + (lane>>4)*4 + r;
        if (grow < M){
          float v = sspf(acc[m][n][r] + bb);
          split_store(v, oh, ol, (size_t)grow*128 + col);
        }
      }
    }
  }
}

// ---------- small kernels ----------
__global__ void transpose_cvt(const float* __restrict__ src, u16* __restrict__ dh, u16* __restrict__ dl, int K, int N){
  __shared__ float t[32][33];
  const float* s = src + (size_t)blockIdx.z * K * N;
  u16* dsth = dh + (size_t)blockIdx.z * K * N;
  u16* dstl = dl + (size_t)blockIdx.z * K * N;
  int n0 = blockIdx.x*32, k0 = blockIdx.y*32;
  for (int dy=threadIdx.y; dy<32; dy+=8){
    int k = k0+dy, n = n0+threadIdx.x;
    if (k<K && n<N) t[dy][threadIdx.x] = s[(size_t)k*N + n];
  }
  __syncthreads();
  for (int dy=threadIdx.y; dy<32; dy+=8){
    int n = n0+dy, k = k0+threadIdx.x;
    if (n<N && k<K) split_store(t[threadIdx.x][dy], dsth, dstl, (size_t)n*K + k);
  }
}

__global__ __launch_bounds__(128) void embed_k(const int* __restrict__ z,
  const float* __restrict__ We1, const float* __restrict__ be1,
  const float* __restrict__ We2, const float* __restrict__ be2,
  const float* __restrict__ We3, const float* __restrict__ be3,
  u16* __restrict__ nh, u16* __restrict__ nl){
  __shared__ float h0[128], h1[128];
  int nid = blockIdx.x, t = threadIdx.x;
  int zz = z[nid];
  h0[t] = sspf(We1[zz*128 + t] + be1[t]);
  __syncthreads();
  float a = be2[t];
  for (int k=0;k<128;k++) a += h0[k]*We2[k*128+t];
  h1[t] = sspf(a);
  __syncthreads();
  float b = be3[t];
  for (int k=0;k<128;k++) b += h1[k]*We3[k*128+t];
  split_store(b, nh, nl, (size_t)nid*128+t);
}

__global__ __launch_bounds__(256) void geom_k(const float* __restrict__ pos,
  const int* __restrict__ ii, const int* __restrict__ jj,
  float* __restrict__ unitv, u16* __restrict__ eh, u16* __restrict__ el){
  int t = threadIdx.x; int e = blockIdx.x*2 + (t>>7); int col = t&127;
  int a = ii[e], b = jj[e];
  float dx = pos[a*3]-pos[b*3], dy=pos[a*3+1]-pos[b*3+1], dz=pos[a*3+2]-pos[b*3+2];
  float dist = sqrtf(dx*dx+dy*dy+dz*dz);
  if (col==0){ float inv=1.f/dist; unitv[e*3]=dx*inv; unitv[e*3+1]=dy*inv; unitv[e*3+2]=dz*inv; }
  const float step = 5.0f/127.0f;
  const float coeff = -0.5f/(step*step);
  float d = dist - step*(float)col;
  float g = __expf(coeff*d*d);
  split_store(g, eh, el, (size_t)e*128+col);
}

__global__ __launch_bounds__(256) void colstats128(const float* __restrict__ m, int M, float* __restrict__ st){
  __shared__ float ls[128], lq[128];
  int t=threadIdx.x; if(t<128){ls[t]=0.f;lq[t]=0.f;} __syncthreads();
  int col=t&127, hf=t>>7; float ps=0.f,pq=0.f;
  int npair=(M+1)>>1;
  for (int pr=blockIdx.x; pr<npair; pr+=gridDim.x){
    int row=pr*2+hf;
    if(row<M){ float v=m[(size_t)row*128+col]; ps+=v; pq+=v*v; }
  }
  atomicAdd(&ls[col],ps); atomicAdd(&lq[col],pq);
  __syncthreads();
  if(t<128){ atomicAdd(&st[t],ls[t]); atomicAdd(&st[128+t],lq[t]); }
}

__global__ __launch_bounds__(256) void node_update_k(u16* __restrict__ nh, u16* __restrict__ nl,
  const float* __restrict__ agg, const float* __restrict__ st,
  const float* __restrict__ g, const float* __restrict__ b, float inv, int Nn)
{
  int t=threadIdx.x; int col=t&127, hf=t>>7;
  float mean = st[col]*inv;
  float var  = st[128+col]*inv - mean*mean;
  float A = g[col]*rsqrtf(var+1e-5f);
  float C = b[col] - A*mean;
  int npair=(Nn+1)>>1;
  for (int pr=blockIdx.x; pr<npair; pr+=gridDim.x){
    int row=pr*2+hf; if(row>=Nn) continue;
    size_t o=(size_t)row*128+col;
    float nv = b2f(nh[o]) + b2f(nl[o]);
    float v = tanhf_(nv + A*agg[o] + C);
    split_store(v, nh, nl, o);
  }
}

__global__ __launch_bounds__(256) void force_k(const u16* __restrict__ fh, const u16* __restrict__ fl,
  const float* __restrict__ Wf3, const float* __restrict__ bf3,
  const float* __restrict__ unitv, const int* __restrict__ ii, float* __restrict__ outp, int Me)
{
  int wv=threadIdx.x>>6, lane=threadIdx.x&63;
  int e = blockIdx.x*4 + wv; if(e>=Me) return;
  size_t o0=(size_t)e*128+lane, o1=o0+64;
  float p = (b2f(fh[o0])+b2f(fl[o0]))*Wf3[lane] + (b2f(fh[o1])+b2f(fl[o1]))*Wf3[64+lane];
  for (int s=32;s>0;s>>=1) p += __shfl_down(p, s);
  if (lane==0){
    float F = p + bf3[0];
    atomicAdd(&outp[ii[e]*3+0], F*unitv[e*3+0]);
    atomicAdd(&outp[ii[e]*3+1], F*unitv[e*3+1]);
    atomicAdd(&outp[ii[e]*3+2], F*unitv[e*3+2]);
  }
}

__global__ void sentinel_k(float* o, int n, float v){
  int i = blockIdx.x*256 + threadIdx.x; if (i<n) o[i]=v;
}

extern "C" void kernel_launch(void* const* d_in, const int* in_sizes, int n_in,
                              void* d_out, int out_size, void* d_ws, size_t ws_size,
                              hipStream_t stream)
{
  (void)in_sizes; (void)n_in;
  const int* z      = (const int*)d_in[0];
  const float* pos  = (const float*)d_in[1];
  const int* ii     = (const int*)d_in[2];
  const int* jj     = (const int*)d_in[3];
  const int* idx_i  = (const int*)d_in[4];
  const int* idx_j  = (const int*)d_in[5];
  const int* idx_k  = (const int*)d_in[6];
  const int* idx_ji = (const int*)d_in[7];
  const int* idx_kj = (const int*)d_in[8];
  const float* We1=(const float*)d_in[9];  const float* be1=(const float*)d_in[10];
  const float* We2=(const float*)d_in[11]; const float* be2=(const float*)d_in[12];
  const float* We3=(const float*)d_in[13]; const float* be3=(const float*)d_in[14];
  const float* Wc1=(const float*)d_in[15]; const float* bc1=(const float*)d_in[16];
  const float* g_c1=(const float*)d_in[17]; const float* b_c1=(const float*)d_in[18];
  const float* g_n=(const float*)d_in[19]; const float* b_n=(const float*)d_in[20];
  const float* Wc2=(const float*)d_in[21]; const float* bc2=(const float*)d_in[22];
  const float* g_c2=(const float*)d_in[23]; const float* b_c2=(const float*)d_in[24];
  const float* Wc3=(const float*)d_in[25]; const float* bc3=(const float*)d_in[26];
  const float* g_c3=(const float*)d_in[27]; const float* b_c3=(const float*)d_in[28];
  const float* g_c22=(const float*)d_in[29]; const float* b_c22=(const float*)d_in[30];
  const float* g_c32=(const float*)d_in[31]; const float* b_c32=(const float*)d_in[32];
  const float* Wf1=(const float*)d_in[33]; const float* bf1=(const float*)d_in[34];
  const float* Wf2=(const float*)d_in[35]; const float* bf2=(const float*)d_in[36];
  const float* Wf3=(const float*)d_in[37]; const float* bf3=(const float*)d_in[38];

  char* ws = (char*)d_ws;
  size_t off=0;
  auto alloc=[&](size_t bb){ size_t o=off; off += (bb+255)&~(size_t)255; return o; };
  u16*   node_h = (u16*)(ws + alloc((size_t)NN*128*2));
  u16*   node_l = (u16*)(ws + alloc((size_t)NN*128*2));
  u16*   edge_h = (u16*)(ws + alloc((size_t)EGN*128*2));
  u16*   edge_l = (u16*)(ws + alloc((size_t)EGN*128*2));
  float* unitv  = (float*)(ws + alloc((size_t)EGN*3*4));
  float* agg    = (float*)(ws + alloc((size_t)NN*128*4));
  float* agg3   = (float*)(ws + alloc((size_t)EGN*128*4));   // reused as f1 planes later
  u16*   wc1h   = (u16*)(ws + alloc((size_t)3*256*256*2));
  u16*   wc1l   = (u16*)(ws + alloc((size_t)3*256*256*2));
  u16*   wc2h   = (u16*)(ws + alloc((size_t)3*256*128*2));
  u16*   wc2l   = (u16*)(ws + alloc((size_t)3*256*128*2));
  u16*   wc3h   = (u16*)(ws + alloc((size_t)3*256*640*2));
  u16*   wc3l   = (u16*)(ws + alloc((size_t)3*256*640*2));
  u16*   wf1h   = (u16*)(ws + alloc((size_t)128*128*2));
  u16*   wf1l   = (u16*)(ws + alloc((size_t)128*128*2));
  u16*   wf2h   = (u16*)(ws + alloc((size_t)128*128*2));
  u16*   wf2l   = (u16*)(ws + alloc((size_t)128*128*2));
  float* stats  = (float*)(ws + alloc(2304*4));

  if (off > ws_size){
    sentinel_k<<<(out_size+255)/256, 256, 0, stream>>>((float*)d_out, out_size, 123456.0f);
    return;
  }

  float* st1 = stats;          // 512 (256 cols)
  float* st2 = stats+512;      // 512
  float* st3 = stats+1024;     // 512
  float* stN = stats+1536;     // 256 (128 cols)
  float* st32= stats+1792;     // 256
  float* st22= stats+2048;     // 256

  u16* f1h = (u16*)agg3;
  u16* f1l = f1h + (size_t)EGN*128;
  u16* f2h = edge_h;
  u16* f2l = edge_l;

  hipMemsetAsync(d_out, 0, (size_t)out_size*4, stream);

  dim3 tb(32,8);
  transpose_cvt<<<dim3(8,8,3),  tb, 0, stream>>>(Wc1, wc1h, wc1l, 256, 256);
  transpose_cvt<<<dim3(8,4,3),  tb, 0, stream>>>(Wc2, wc2h, wc2l, 128, 256);
  transpose_cvt<<<dim3(8,20,3), tb, 0, stream>>>(Wc3, wc3h, wc3l, 640, 256);
  transpose_cvt<<<dim3(4,4,1),  tb, 0, stream>>>(Wf1, wf1h, wf1l, 128, 128);
  transpose_cvt<<<dim3(4,4,1),  tb, 0, stream>>>(Wf2, wf2h, wf2l, 128, 128);

  embed_k<<<NN,128,0,stream>>>(z, We1,be1,We2,be2,We3,be3, node_h, node_l);
  geom_k<<<EGN/2,256,0,stream>>>(pos, ii, jj, unitv, edge_h, edge_l);

  const int gE64  = (EGN+63)/64;    // 3125
  const int gT64  = (TTN+63)/64;    // 4688
  Segs dummy{};
  const float invE = 1.0f/EGN, invT = 1.0f/TTN, invN = 1.0f/NN;

  for (int l=0;l<LLN;l++){
    hipMemsetAsync(stats, 0, 2304*4, stream);
    hipMemsetAsync(agg,  0, (size_t)NN*128*4, stream);
    hipMemsetAsync(agg3, 0, (size_t)EGN*128*4, stream);

    const u16* w1h = wc1h + l*256*256; const u16* w1l = wc1l + l*256*256;
    const u16* w2h = wc2h + l*256*128; const u16* w2l = wc2l + l*256*128;
    const u16* w3h = wc3h + l*256*640; const u16* w3l = wc3l + l*256*640;

    // ---- NodeUpdate: c1 ----
    Segs s1{};
    s1.sh[0]=node_h; s1.sl[0]=node_l; s1.idx[0]=ii;      s1.coff[0]=0;
    s1.sh[1]=node_h; s1.sl[1]=node_l; s1.idx[1]=ii;      s1.coff[1]=128;
    s1.sh[2]=edge_h; s1.sl[2]=edge_l; s1.idx[2]=nullptr; s1.coff[2]=0;
    s1.sh[3]=edge_h; s1.sl[3]=edge_l; s1.idx[3]=nullptr; s1.coff[3]=128;
    gemm_stats<false><<<gE64,256,0,stream>>>(EGN, 4, s1, nullptr,nullptr,nullptr,nullptr,
                                             w1h, 512, bc1+l*256, st1);
    gemm_pair<2,false,0><<<gE64,256,0,stream>>>(EGN, 4, s1, nullptr,nullptr,nullptr,nullptr,
        w1h, w1l, 512, bc1+l*256,
        st1, g_c1+l*256, b_c1+l*256, invE,
        ii, agg,
        nullptr,nullptr,nullptr, nullptr,nullptr,nullptr, 0.f,
        nullptr, nullptr, nullptr, nullptr);
    colstats128<<<256,256,0,stream>>>(agg, NN, stN);
    node_update_k<<<2048,256,0,stream>>>(node_h, node_l, agg, stN, g_n+l*128, b_n+l*128, invN, NN);

    // ---- EdgeUpdate triplet term: c3 ----
    Segs s3{};
    s3.sh[0]=node_h; s3.sl[0]=node_l; s3.idx[0]=idx_i;  s3.coff[0]=0;
    s3.sh[1]=node_h; s3.sl[1]=node_l; s3.idx[1]=idx_i;  s3.coff[1]=128;
    s3.sh[2]=node_h; s3.sl[2]=node_l; s3.idx[2]=idx_j;  s3.coff[2]=0;
    s3.sh[3]=node_h; s3.sl[3]=node_l; s3.idx[3]=idx_j;  s3.coff[3]=128;
    s3.sh[4]=node_h; s3.sl[4]=node_l; s3.idx[4]=idx_k;  s3.coff[4]=0;
    s3.sh[5]=node_h; s3.sl[5]=node_l; s3.idx[5]=idx_k;  s3.coff[5]=128;
    s3.sh[6]=edge_h; s3.sl[6]=edge_l; s3.idx[6]=idx_ji; s3.coff[6]=0;
    s3.sh[7]=edge_h; s3.sl[7]=edge_l; s3.idx[7]=idx_ji; s3.coff[7]=128;
    s3.sh[8]=edge_h; s3.sl[8]=edge_l; s3.idx[8]=idx_kj; s3.coff[8]=0;
    s3.sh[9]=edge_h; s3.sl[9]=edge_l; s3.idx[9]=idx_kj; s3.coff[9]=128;
    gemm_stats<false><<<gT64,256,0,stream>>>(TTN, 10, s3, nullptr,nullptr,nullptr,nullptr,
                                             w3h, 1280, bc3+l*256, st3);
    gemm_pair<2,false,0><<<gT64,256,0,stream>>>(TTN, 10, s3, nullptr,nullptr,nullptr,nullptr,
        w3h, w3l, 1280, bc3+l*256,
        st3, g_c3+l*256, b_c3+l*256, invT,
        idx_ji, agg3,
        nullptr,nullptr,nullptr, nullptr,nullptr,nullptr, 0.f,
        nullptr, nullptr, nullptr, nullptr);
    colstats128<<<1024,256,0,stream>>>(agg3, EGN, st32);

    // ---- EdgeUpdate pair term: c2 (prod built on the fly) ----
    gemm_stats<true><<<gE64,256,0,stream>>>(EGN, 2, dummy, node_h,node_l,ii,jj,
                                            w2h, 256, bc2+l*256, st2);
    gemm_pair<1,true,2><<<gE64,256,0,stream>>>(EGN, 2, dummy, node_h,node_l,ii,jj,
        w2h, nullptr, 256, bc2+l*256,
        st2, g_c2+l*256, b_c2+l*256, invE,
        nullptr, nullptr,
        nullptr,nullptr,nullptr, nullptr,nullptr,nullptr, 0.f,
        nullptr, nullptr, nullptr, st22);
    gemm_pair<2,true,1><<<gE64,256,0,stream>>>(EGN, 2, dummy, node_h,node_l,ii,jj,
        w2h, w2l, 256, bc2+l*256,
        st2, g_c2+l*256, b_c2+l*256, invE,
        nullptr, nullptr,
        st22, g_c22+l*128, b_c22+l*128, st32, g_c32+l*128, b_c32+l*128, invE,
        agg3, edge_h, edge_l, nullptr);
  }

  // ---- ForcePredictor ----
  Segs sf1{}; sf1.sh[0]=edge_h; sf1.sl[0]=edge_l; sf1.idx[0]=nullptr; sf1.coff[0]=0;
              sf1.sh[1]=edge_h; sf1.sl[1]=edge_l; sf1.idx[1]=nullptr; sf1.coff[1]=128;
  gemm_force<<<gE64,256,0,stream>>>(EGN, sf1, wf1h, wf1l, 256, bf1, f1h, f1l);
  Segs sf2{}; sf2.sh[0]=f1h; sf2.sl[0]=f1l; sf2.idx[0]=nullptr; sf2.coff[0]=0;
              sf2.sh[1]=f1h; sf2.sl[1]=f1l; sf2.idx[1]=nullptr; sf2.coff[1]=128;
  gemm_force<<<gE64,256,0,stream>>>(EGN, sf2, wf2h, wf2l, 256, bf2, f2h, f2l);
  force_k<<<(EGN+3)/4,256,0,stream>>>(f2h, f2l, Wf3, bf3, unitv, ii, (float*)d_out, EGN);
}